// Round 10
// baseline (380.087 us; speedup 1.0000x reference)
//
#include <hip/hip_runtime.h>
#include <hip/hip_bf16.h>

typedef unsigned short ushort;
typedef __bf16 bf16x8 __attribute__((ext_vector_type(8)));
typedef float f32x4 __attribute__((ext_vector_type(4)));

__device__ __forceinline__ ushort f2bu(float f) {
  __hip_bfloat16 h = __float2bfloat16(f);
  return *(ushort*)&h;
}
__device__ __forceinline__ f32x4 mfma16(bf16x8 a, bf16x8 b, f32x4 c) {
  return __builtin_amdgcn_mfma_f32_16x16x32_bf16(a, b, c, 0, 0, 0);
}
__device__ __forceinline__ float fexp2(float x) { return __builtin_amdgcn_exp2f(x); }

// ---------------------------------------------------------------------------
// Problem constants: B=8, C=64, E=64, H=W=64, N=4096, 3C=192, k_val=2048
// Inputs fp32 / output fp32 (proven round 3). All GEMMs on MFMA.
// Q pre-scaled by 0.125*log2(e) so E = 2^score = exp(s/8): one v_exp, no mul.
// k_sumexp: 32-q blocks (1024 total) for 2x occupancy; l reduced in-block.
// ---------------------------------------------------------------------------

// Kernel 1: f_flat[b][n][0:64]=1x1 conv, [64:128]=dw3x3, [128:192]=dw5x5
__global__ __launch_bounds__(256) void k_conv(
    const float* __restrict__ x, const float* __restrict__ w1, const float* __restrict__ b1,
    const float* __restrict__ w3, const float* __restrict__ b3,
    const float* __restrict__ w5, const float* __restrict__ b5,
    ushort* __restrict__ f) {
  __shared__ float xs[64][64];
  __shared__ float w1s[64 * 65];
  __shared__ float w3s[576];
  __shared__ float w5s[1600];
  __shared__ float bs1[64], bs3[64], bs5[64];
  const int tid = threadIdx.x;
  const int y = blockIdx.x;
  const int b = blockIdx.y;
  for (int i = tid; i < 4096; i += 256) {
    int ch = i >> 6, w = i & 63;
    xs[ch][w] = x[((size_t)(b * 64 + ch) * 64 + y) * 64 + w];
  }
  for (int i = tid; i < 4096; i += 256) w1s[(i >> 6) * 65 + (i & 63)] = w1[i];
  for (int i = tid; i < 576; i += 256) w3s[i] = w3[i];
  for (int i = tid; i < 1600; i += 256) w5s[i] = w5[i];
  if (tid < 64) { bs1[tid] = b1[tid]; bs3[tid] = b3[tid]; bs5[tid] = b5[tid]; }
  __syncthreads();
  const int px = tid & 63;
  const int cg = tid >> 6;
  const int cb = cg * 16;
  ushort* fo = f + ((size_t)b * 4096 + y * 64 + px) * 192;
  float a1[16];
#pragma unroll
  for (int j = 0; j < 16; j++) a1[j] = bs1[cb + j];
  for (int ic = 0; ic < 64; ic++) {
    float xv = xs[ic][px];
#pragma unroll
    for (int j = 0; j < 16; j++) a1[j] += w1s[(cb + j) * 65 + ic] * xv;
  }
#pragma unroll
  for (int j = 0; j < 16; j++) fo[cb + j] = f2bu(a1[j]);
#pragma unroll 4
  for (int j = 0; j < 16; j++) {
    int c = cb + j;
    const float* xc = x + (size_t)(b * 64 + c) * 4096;
    float a3 = bs3[c], a5 = bs5[c];
#pragma unroll
    for (int dy = 0; dy < 5; dy++) {
      int yy = y + dy - 2;
      if (yy < 0 || yy >= 64) continue;
      const float* xr = xc + yy * 64;
#pragma unroll
      for (int dx = 0; dx < 5; dx++) {
        int wx = px + dx - 2;
        float v = (wx >= 0 && wx < 64) ? xr[wx] : 0.f;
        a5 += w5s[c * 25 + dy * 5 + dx] * v;
        if (dy >= 1 && dy <= 3 && dx >= 1 && dx <= 3)
          a3 += w3s[c * 9 + (dy - 1) * 3 + (dx - 1)] * v;
      }
    }
    fo[64 + c] = f2bu(a3);
    fo[128 + c] = f2bu(a5);
  }
}

// Kernel 1b: convert qw/kw/vw fp32 -> contiguous bf16 buffer [3][64][192].
__global__ __launch_bounds__(256) void k_w2b(
    const float* __restrict__ qw, const float* __restrict__ kw,
    const float* __restrict__ vw, ushort* __restrict__ Wb) {
  int i = blockIdx.x * 256 + threadIdx.x;   // 36864 total
  const float* src = (i < 12288) ? qw : (i < 24576) ? kw : vw;
  int off = (i < 12288) ? i : (i < 24576) ? (i - 12288) : (i - 24576);
  Wb[i] = f2bu(src[off]);
}

// Kernel 2: Q/K/V = F @ {qw,kw,vw}^T + bias via MFMA. 64 rows/block, 4 waves.
// Q pre-scaled by 0.125*log2(e) (exp -> exp2 downstream).
__global__ __launch_bounds__(256) void k_qkv(
    const ushort* __restrict__ F, const ushort* __restrict__ Wb,
    const float* __restrict__ qb, const float* __restrict__ kb,
    const float* __restrict__ vb,
    ushort* __restrict__ Q, ushort* __restrict__ K, ushort* __restrict__ V) {
  __shared__ __align__(16) ushort fs[64][200];   // stride 200: even granule spread
  const int tid = threadIdx.x;
  const int w = tid >> 6;
  const int lane = tid & 63;
  const int col = lane & 15;
  const int quad = lane >> 4;
  const size_t rowbase = (size_t)blockIdx.x * 64;
  for (int i = tid; i < 1536; i += 256) {   // 16B chunks: 64*192*2/16
    int r = i / 24, c8 = i % 24;
    *(uint4*)&fs[r][c8 * 8] = *(const uint4*)&F[rowbase * 192 + (size_t)i * 8];
  }
  __syncthreads();
  bf16x8 af[6];
#pragma unroll
  for (int kk = 0; kk < 6; kk++)
    af[kk] = *(const bf16x8*)&fs[w * 16 + col][kk * 32 + quad * 8];
  ushort* const outp[3] = {Q, K, V};
  const float* const bp[3] = {qb, kb, vb};
#pragma unroll
  for (int sel = 0; sel < 3; sel++) {
    const ushort* wsel = Wb + sel * 12288;
    const float sc = (sel == 0) ? 0.125f * 1.44269504088896f : 1.0f;
#pragma unroll
    for (int ntl = 0; ntl < 4; ntl++) {
      const ushort* brow = wsel + (ntl * 16 + col) * 192 + quad * 8;
      f32x4 acc = {0.f, 0.f, 0.f, 0.f};
#pragma unroll
      for (int kk = 0; kk < 6; kk++) {
        bf16x8 bf = *(const bf16x8*)&brow[kk * 32];
        acc = mfma16(af[kk], bf, acc);
      }
      float bv = bp[sel][ntl * 16 + col];
#pragma unroll
      for (int r = 0; r < 4; r++)
        outp[sel][(rowbase + w * 16 + quad * 4 + r) * 64 + ntl * 16 + col] =
            f2bu((acc[r] + bv) * sc);
    }
  }
}

// Kernel 3: MFMA flash sweeps, 32-q blocks, barrier-free K-loops.
// Sweep 1: l_q = sum_k 2^(s_qk). Sweep 2: IP[b*128+qt][k] = sum_q E_qk/l_q.
__global__ __launch_bounds__(256) void k_sumexp(
    const ushort* __restrict__ Qb, const ushort* __restrict__ Kb,
    float* __restrict__ Lo, float* __restrict__ IP) {
  __shared__ float red[4][32];
  __shared__ float lred[32];
  const int tid = threadIdx.x;
  const int b = blockIdx.x & 7;          // XCD swizzle: batch -> XCD
  const int qt = blockIdx.x >> 3;        // 0..127 (32-q tiles)
  const int lane = tid & 63;
  const int w = tid >> 6;
  const int col = lane & 15;
  const int quad = lane >> 4;
  const size_t qbase = (size_t)b * 4096 + qt * 32;
  const size_t kbase = (size_t)b * 4096;
  bf16x8 af[2][2];   // Q A-frags, direct from global (row-contiguous)
#pragma unroll
  for (int t = 0; t < 2; t++)
#pragma unroll
    for (int h = 0; h < 2; h++)
      af[t][h] = *(const bf16x8*)&Qb[(qbase + t * 16 + col) * 64 + quad * 8 + h * 32];
  const ushort* kp = &Kb[(kbase + w * 16 + col) * 64 + quad * 8];
  float lacc[2][4];
#pragma unroll
  for (int t = 0; t < 2; t++)
#pragma unroll
    for (int r = 0; r < 4; r++) lacc[t][r] = 0.f;
  bf16x8 nb0 = *(const bf16x8*)kp;
  bf16x8 nb1 = *(const bf16x8*)(kp + 32);
  for (int kt = 0; kt < 64; kt++) {
    bf16x8 b0 = nb0, b1 = nb1;
    if (kt < 63) {
      nb0 = *(const bf16x8*)(kp + (size_t)(kt + 1) * 4096);
      nb1 = *(const bf16x8*)(kp + (size_t)(kt + 1) * 4096 + 32);
    }
#pragma unroll
    for (int t = 0; t < 2; t++) {
      f32x4 acc = {0.f, 0.f, 0.f, 0.f};
      acc = mfma16(af[t][0], b0, acc);
      acc = mfma16(af[t][1], b1, acc);
#pragma unroll
      for (int r = 0; r < 4; r++) lacc[t][r] += fexp2(acc[r]);
    }
  }
  // reduce over the wave's 16 key-cols, then across waves
#pragma unroll
  for (int t = 0; t < 2; t++)
#pragma unroll
    for (int r = 0; r < 4; r++) {
      float v = lacc[t][r];
      v += __shfl_xor(v, 1); v += __shfl_xor(v, 2);
      v += __shfl_xor(v, 4); v += __shfl_xor(v, 8);
      if (col == 0) red[w][t * 16 + quad * 4 + r] = v;
    }
  __syncthreads();
  if (tid < 32) {
    float l = red[0][tid] + red[1][tid] + red[2][tid] + red[3][tid];
    Lo[qbase + tid] = l;
    lred[tid] = 1.f / l;
  }
  __syncthreads();
  float linv[2][4];
#pragma unroll
  for (int t = 0; t < 2; t++)
#pragma unroll
    for (int r = 0; r < 4; r++) linv[t][r] = lred[t * 16 + quad * 4 + r];
  nb0 = *(const bf16x8*)kp;
  nb1 = *(const bf16x8*)(kp + 32);
  for (int kt = 0; kt < 64; kt++) {
    bf16x8 b0 = nb0, b1 = nb1;
    if (kt < 63) {
      nb0 = *(const bf16x8*)(kp + (size_t)(kt + 1) * 4096);
      nb1 = *(const bf16x8*)(kp + (size_t)(kt + 1) * 4096 + 32);
    }
    float ip = 0.f;
#pragma unroll
    for (int t = 0; t < 2; t++) {
      f32x4 acc = {0.f, 0.f, 0.f, 0.f};
      acc = mfma16(af[t][0], b0, acc);
      acc = mfma16(af[t][1], b1, acc);
#pragma unroll
      for (int r = 0; r < 4; r++) ip += fexp2(acc[r]) * linv[t][r];
    }
    ip += __shfl_xor(ip, 16);   // sum the 4 quad-groups (rows)
    ip += __shfl_xor(ip, 32);
    if (quad == 0)
      IP[((size_t)(b * 128 + qt)) * 4096 + kt * 64 + w * 16 + col] = ip;
  }
}

// Kernel 4a: imp[b][k] = sum_r IP[b*128+r][k] (fixed r order -> deterministic).
__global__ __launch_bounds__(256) void k_impsum(
    const float* __restrict__ IP, float* __restrict__ imp) {
  const int tid = threadIdx.x;
  const int b = blockIdx.y;
  const int col = blockIdx.x * 256 + tid;
  const float* p = IP + (size_t)b * 128 * 4096 + col;
  float s = 0.f;
#pragma unroll 8
  for (int r = 0; r < 128; r++) s += p[(size_t)r * 4096];
  imp[(size_t)b * 4096 + col] = s;
}

// Kernel 4b: exact top-2048 by rank counting (matches lax.top_k ties) and
// rank-indexed gather into compacted Kc/Vc.
__global__ __launch_bounds__(256) void k_mask2c(
    const float* __restrict__ imp, const ushort* __restrict__ Kb,
    const ushort* __restrict__ Vb, ushort* __restrict__ Kc,
    ushort* __restrict__ Vc) {
  __shared__ __align__(16) float imps[4096];
  __shared__ int part[4][64];
  const int tid = threadIdx.x;
  const int b = blockIdx.y;
  const int base = blockIdx.x * 64;
  for (int i = tid; i < 4096; i += 256) imps[i] = imp[(size_t)b * 4096 + i];
  __syncthreads();
  const int cand = tid & 63;
  const int seg = tid >> 6;
  const int k = base + cand;
  const float v = imps[k];
  int cnt = 0;
  const int j0 = seg * 1024;
  for (int j = j0; j < j0 + 1024; j += 4) {
    float4 a = *(const float4*)&imps[j];
    cnt += (a.x > v) ? 1 : ((a.x == v && (j + 0) < k) ? 1 : 0);
    cnt += (a.y > v) ? 1 : ((a.y == v && (j + 1) < k) ? 1 : 0);
    cnt += (a.z > v) ? 1 : ((a.z == v && (j + 2) < k) ? 1 : 0);
    cnt += (a.w > v) ? 1 : ((a.w == v && (j + 3) < k) ? 1 : 0);
  }
  part[seg][cand] = cnt;
  __syncthreads();
  const int c = part[0][cand] + part[1][cand] + part[2][cand] + part[3][cand];
  if (c < 2048) {
    const ushort* ksrc = &Kb[((size_t)b * 4096 + k) * 64 + seg * 16];
    const ushort* vsrc = &Vb[((size_t)b * 4096 + k) * 64 + seg * 16];
    ushort* kdst = &Kc[((size_t)b * 2048 + c) * 64 + seg * 16];
    ushort* vdst = &Vc[((size_t)b * 2048 + c) * 64 + seg * 16];
    *(uint4*)kdst = *(const uint4*)ksrc;
    *(uint4*)(kdst + 8) = *(const uint4*)(ksrc + 8);
    *(uint4*)vdst = *(const uint4*)vsrc;
    *(uint4*)(vdst + 8) = *(const uint4*)(vsrc + 8);
  }
}

// Kernel 5: MFMA attention output + projection over COMPACTED keys (32 tiles).
__global__ __launch_bounds__(256) void k_attn_out(
    const ushort* __restrict__ Qb, const ushort* __restrict__ Kc,
    const ushort* __restrict__ Vc, const float* __restrict__ Lo,
    const float* __restrict__ owp, const float* __restrict__ obp,
    float* __restrict__ out) {
  __shared__ __align__(16) ushort Vt[64][72];   // V transposed: [c][k]
  __shared__ __align__(16) ushort Ps[64][72];   // P (then AO) in A-layout
  __shared__ __align__(16) ushort ows[64][72];  // ow bf16
  __shared__ float dred[4][64];
  __shared__ float lqs[64];
  const int tid = threadIdx.x;
  const int b = blockIdx.x & 7;
  const int qt = blockIdx.x >> 3;
  const int lane = tid & 63;
  const int w = tid >> 6;
  const int col = lane & 15;
  const int quad = lane >> 4;
  const size_t qbase = (size_t)b * 4096 + qt * 64;
  const size_t kbase = (size_t)b * 2048;   // compacted
  bf16x8 af[4][2];
#pragma unroll
  for (int t = 0; t < 4; t++)
#pragma unroll
    for (int h = 0; h < 2; h++)
      af[t][h] = *(const bf16x8*)&Qb[(qbase + t * 16 + col) * 64 + quad * 8 + h * 32];
  for (int i = tid; i < 4096; i += 256) ows[i >> 6][i & 63] = f2bu(owp[i]);
  if (tid < 64) lqs[tid] = Lo[qbase + tid];
  f32x4 pv[4];
  float dpacc[4][4];
#pragma unroll
  for (int t = 0; t < 4; t++) {
    pv[t] = (f32x4){0.f, 0.f, 0.f, 0.f};
#pragma unroll
    for (int r = 0; r < 4; r++) dpacc[t][r] = 0.f;
  }
  const int vrow = tid & 63;   // Vt staging: lane covers one V row,
  const int vch = tid >> 6;    // wave-indexed c-chunk -> conflict-free writes
  const ushort* kp = &Kc[(kbase + w * 16 + col) * 64 + quad * 8];
  bf16x8 nb0 = *(const bf16x8*)kp;
  bf16x8 nb1 = *(const bf16x8*)(kp + 32);
  for (int kt = 0; kt < 32; kt++) {
    __syncthreads();   // prev iteration done reading Vt/Ps
    {
      const ushort* vsrc = &Vc[(kbase + kt * 64 + vrow) * 64 + vch * 16];
      uint4 v0 = *(const uint4*)vsrc;
      uint4 v1 = *(const uint4*)(vsrc + 8);
      ushort tmp[16];
      *(uint4*)&tmp[0] = v0;
      *(uint4*)&tmp[8] = v1;
#pragma unroll
      for (int j = 0; j < 16; j++) Vt[vch * 16 + j][vrow] = tmp[j];
    }
    bf16x8 b0 = nb0, b1 = nb1;
    if (kt < 31) {
      nb0 = *(const bf16x8*)(kp + (size_t)(kt + 1) * 4096);
      nb1 = *(const bf16x8*)(kp + (size_t)(kt + 1) * 4096 + 32);
    }
#pragma unroll
    for (int t = 0; t < 4; t++) {
      f32x4 acc = {0.f, 0.f, 0.f, 0.f};
      acc = mfma16(af[t][0], b0, acc);
      acc = mfma16(af[t][1], b1, acc);
#pragma unroll
      for (int r = 0; r < 4; r++) {
        float p = fexp2(acc[r]);
        dpacc[t][r] += p;
        Ps[t * 16 + quad * 4 + r][w * 16 + col] = f2bu(p);
      }
    }
    __syncthreads();   // Vt + Ps visible
    bf16x8 v0f = *(const bf16x8*)&Vt[w * 16 + col][quad * 8];
    bf16x8 v1f = *(const bf16x8*)&Vt[w * 16 + col][quad * 8 + 32];
#pragma unroll
    for (int t = 0; t < 4; t++) {
      bf16x8 p0 = *(const bf16x8*)&Ps[t * 16 + col][quad * 8];
      bf16x8 p1 = *(const bf16x8*)&Ps[t * 16 + col][quad * 8 + 32];
      pv[t] = mfma16(p0, v0f, pv[t]);
      pv[t] = mfma16(p1, v1f, pv[t]);
    }
  }
  // den: reduce dpacc over the wave's 16 cols, then across waves
#pragma unroll
  for (int t = 0; t < 4; t++)
#pragma unroll
    for (int r = 0; r < 4; r++) {
      float v = dpacc[t][r];
      v += __shfl_xor(v, 1); v += __shfl_xor(v, 2);
      v += __shfl_xor(v, 4); v += __shfl_xor(v, 8);
      if (col == 0) dred[w][t * 16 + quad * 4 + r] = v;
    }
  __syncthreads();
  // normalize pv -> AO (bf16, A-layout in Ps)
#pragma unroll
  for (int t = 0; t < 4; t++)
#pragma unroll
    for (int r = 0; r < 4; r++) {
      int q = t * 16 + quad * 4 + r;
      float den = dred[0][q] + dred[1][q] + dred[2][q] + dred[3][q] + 1e-8f * lqs[q];
      Ps[q][w * 16 + col] = f2bu(pv[t][r] / den);
    }
  __syncthreads();
  // projection: out[q][co] = sum_c AO[q][c]*ow[co][c] + ob[co]
  bf16x8 w0 = *(const bf16x8*)&ows[w * 16 + col][quad * 8];
  bf16x8 w1 = *(const bf16x8*)&ows[w * 16 + col][quad * 8 + 32];
  const float obv = obp[w * 16 + col];
#pragma unroll
  for (int t = 0; t < 4; t++) {
    bf16x8 p0 = *(const bf16x8*)&Ps[t * 16 + col][quad * 8];
    bf16x8 p1 = *(const bf16x8*)&Ps[t * 16 + col][quad * 8 + 32];
    f32x4 oc = {0.f, 0.f, 0.f, 0.f};
    oc = mfma16(p0, w0, oc);
    oc = mfma16(p1, w1, oc);
#pragma unroll
    for (int r = 0; r < 4; r++) {
      int q = t * 16 + quad * 4 + r;
      int co = w * 16 + col;
      out[((size_t)(b * 64 + co)) * 4096 + qt * 64 + q] = oc[r] + obv;
    }
  }
}

extern "C" void kernel_launch(void* const* d_in, const int* in_sizes, int n_in,
                              void* d_out, int out_size, void* d_ws, size_t ws_size,
                              hipStream_t stream) {
  const float* x  = (const float*)d_in[0];
  const float* w1 = (const float*)d_in[1];
  const float* b1 = (const float*)d_in[2];
  const float* w3 = (const float*)d_in[3];
  const float* b3 = (const float*)d_in[4];
  const float* w5 = (const float*)d_in[5];
  const float* b5 = (const float*)d_in[6];
  const float* qw = (const float*)d_in[7];
  const float* qb = (const float*)d_in[8];
  const float* kw = (const float*)d_in[9];
  const float* kb = (const float*)d_in[10];
  const float* vw = (const float*)d_in[11];
  const float* vb = (const float*)d_in[12];
  const float* ow = (const float*)d_in[13];
  const float* ob = (const float*)d_in[14];
  float* out = (float*)d_out;
  float* ws = (float*)d_ws;
  // workspace layout (float units): ~46.4 MB total
  ushort* F   = (ushort*)ws;                  // 6,291,456 us = 3,145,728 f
  ushort* Qb  = (ushort*)(ws + 3145728);      // 2,097,152 us = 1,048,576 f
  ushort* Kb  = (ushort*)(ws + 4194304);      // 1,048,576 f
  ushort* Vb  = (ushort*)(ws + 5242880);      // 1,048,576 f
  float*  Lo  = ws + 6291456;                 // 32,768 f
  float*  IP  = ws + 6324224;                 // 4,194,304 f (128 rows/batch)
  float*  imp = ws + 10518528;                // 32,768 f
  ushort* Kc  = (ushort*)(ws + 10551296);     // 1,048,576 us = 524,288 f
  ushort* Vc  = (ushort*)(ws + 11075584);     // 524,288 f
  ushort* Wb  = (ushort*)(ws + 11599872);     // 36,864 us

  k_w2b<<<144, 256, 0, stream>>>(qw, kw, vw, Wb);
  k_conv<<<dim3(64, 8), 256, 0, stream>>>(x, w1, b1, w3, b3, w5, b5, F);
  k_qkv<<<512, 256, 0, stream>>>(F, Wb, qb, kb, vb, Qb, Kb, Vb);
  k_sumexp<<<1024, 256, 0, stream>>>(Qb, Kb, Lo, IP);
  k_impsum<<<dim3(16, 8), 256, 0, stream>>>(IP, imp);
  k_mask2c<<<dim3(64, 8), 256, 0, stream>>>(imp, Kb, Vb, Kc, Vc);
  k_attn_out<<<512, 256, 0, stream>>>(Qb, Kc, Vc, Lo, ow, ob, out);
}

// Round 11
// 356.934 us; speedup vs baseline: 1.0649x; 1.0649x over previous
//
#include <hip/hip_runtime.h>
#include <hip/hip_bf16.h>

typedef unsigned short ushort;
typedef __bf16 bf16x8 __attribute__((ext_vector_type(8)));
typedef float f32x4 __attribute__((ext_vector_type(4)));

__device__ __forceinline__ ushort f2bu(float f) {
  __hip_bfloat16 h = __float2bfloat16(f);
  return *(ushort*)&h;
}
__device__ __forceinline__ f32x4 mfma16(bf16x8 a, bf16x8 b, f32x4 c) {
  return __builtin_amdgcn_mfma_f32_16x16x32_bf16(a, b, c, 0, 0, 0);
}
__device__ __forceinline__ float fexp2(float x) { return __builtin_amdgcn_exp2f(x); }

// ---------------------------------------------------------------------------
// Problem constants: B=8, C=64, E=64, H=W=64, N=4096, 3C=192, k_val=2048
// Inputs fp32 / output fp32 (proven round 3). All GEMMs on MFMA.
// Q pre-scaled by 0.125*log2(e): E = 2^score = exp(s/8), single v_exp.
// Round 11: K-SPLIT sumexp (64-q blocks keep 8-MFMA-per-K-load density;
// 2x blocks via half key-range each). Round-10's q-split regressed: it
// halved compute per K-byte -> load-latency bound.
// ---------------------------------------------------------------------------

// Kernel 1: f_flat[b][n][0:64]=1x1 conv, [64:128]=dw3x3, [128:192]=dw5x5
__global__ __launch_bounds__(256) void k_conv(
    const float* __restrict__ x, const float* __restrict__ w1, const float* __restrict__ b1,
    const float* __restrict__ w3, const float* __restrict__ b3,
    const float* __restrict__ w5, const float* __restrict__ b5,
    ushort* __restrict__ f) {
  __shared__ float xs[64][64];
  __shared__ float w1s[64 * 65];
  __shared__ float w3s[576];
  __shared__ float w5s[1600];
  __shared__ float bs1[64], bs3[64], bs5[64];
  const int tid = threadIdx.x;
  const int y = blockIdx.x;
  const int b = blockIdx.y;
  for (int i = tid; i < 4096; i += 256) {
    int ch = i >> 6, w = i & 63;
    xs[ch][w] = x[((size_t)(b * 64 + ch) * 64 + y) * 64 + w];
  }
  for (int i = tid; i < 4096; i += 256) w1s[(i >> 6) * 65 + (i & 63)] = w1[i];
  for (int i = tid; i < 576; i += 256) w3s[i] = w3[i];
  for (int i = tid; i < 1600; i += 256) w5s[i] = w5[i];
  if (tid < 64) { bs1[tid] = b1[tid]; bs3[tid] = b3[tid]; bs5[tid] = b5[tid]; }
  __syncthreads();
  const int px = tid & 63;
  const int cg = tid >> 6;
  const int cb = cg * 16;
  ushort* fo = f + ((size_t)b * 4096 + y * 64 + px) * 192;
  float a1[16];
#pragma unroll
  for (int j = 0; j < 16; j++) a1[j] = bs1[cb + j];
  for (int ic = 0; ic < 64; ic++) {
    float xv = xs[ic][px];
#pragma unroll
    for (int j = 0; j < 16; j++) a1[j] += w1s[(cb + j) * 65 + ic] * xv;
  }
#pragma unroll
  for (int j = 0; j < 16; j++) fo[cb + j] = f2bu(a1[j]);
#pragma unroll 4
  for (int j = 0; j < 16; j++) {
    int c = cb + j;
    const float* xc = x + (size_t)(b * 64 + c) * 4096;
    float a3 = bs3[c], a5 = bs5[c];
#pragma unroll
    for (int dy = 0; dy < 5; dy++) {
      int yy = y + dy - 2;
      if (yy < 0 || yy >= 64) continue;
      const float* xr = xc + yy * 64;
#pragma unroll
      for (int dx = 0; dx < 5; dx++) {
        int wx = px + dx - 2;
        float v = (wx >= 0 && wx < 64) ? xr[wx] : 0.f;
        a5 += w5s[c * 25 + dy * 5 + dx] * v;
        if (dy >= 1 && dy <= 3 && dx >= 1 && dx <= 3)
          a3 += w3s[c * 9 + (dy - 1) * 3 + (dx - 1)] * v;
      }
    }
    fo[64 + c] = f2bu(a3);
    fo[128 + c] = f2bu(a5);
  }
}

// Kernel 1b: convert qw/kw/vw fp32 -> contiguous bf16 buffer [3][64][192].
__global__ __launch_bounds__(256) void k_w2b(
    const float* __restrict__ qw, const float* __restrict__ kw,
    const float* __restrict__ vw, ushort* __restrict__ Wb) {
  int i = blockIdx.x * 256 + threadIdx.x;   // 36864 total
  const float* src = (i < 12288) ? qw : (i < 24576) ? kw : vw;
  int off = (i < 12288) ? i : (i < 24576) ? (i - 12288) : (i - 24576);
  Wb[i] = f2bu(src[off]);
}

// Kernel 2: Q/K/V = F @ {qw,kw,vw}^T + bias via MFMA. 64 rows/block, 4 waves.
// Q pre-scaled by 0.125*log2(e) (exp -> exp2 downstream).
__global__ __launch_bounds__(256) void k_qkv(
    const ushort* __restrict__ F, const ushort* __restrict__ Wb,
    const float* __restrict__ qb, const float* __restrict__ kb,
    const float* __restrict__ vb,
    ushort* __restrict__ Q, ushort* __restrict__ K, ushort* __restrict__ V) {
  __shared__ __align__(16) ushort fs[64][200];   // stride 200: even granule spread
  const int tid = threadIdx.x;
  const int w = tid >> 6;
  const int lane = tid & 63;
  const int col = lane & 15;
  const int quad = lane >> 4;
  const size_t rowbase = (size_t)blockIdx.x * 64;
  for (int i = tid; i < 1536; i += 256) {   // 16B chunks: 64*192*2/16
    int r = i / 24, c8 = i % 24;
    *(uint4*)&fs[r][c8 * 8] = *(const uint4*)&F[rowbase * 192 + (size_t)i * 8];
  }
  __syncthreads();
  bf16x8 af[6];
#pragma unroll
  for (int kk = 0; kk < 6; kk++)
    af[kk] = *(const bf16x8*)&fs[w * 16 + col][kk * 32 + quad * 8];
  ushort* const outp[3] = {Q, K, V};
  const float* const bp[3] = {qb, kb, vb};
#pragma unroll
  for (int sel = 0; sel < 3; sel++) {
    const ushort* wsel = Wb + sel * 12288;
    const float sc = (sel == 0) ? 0.125f * 1.44269504088896f : 1.0f;
#pragma unroll
    for (int ntl = 0; ntl < 4; ntl++) {
      const ushort* brow = wsel + (ntl * 16 + col) * 192 + quad * 8;
      f32x4 acc = {0.f, 0.f, 0.f, 0.f};
#pragma unroll
      for (int kk = 0; kk < 6; kk++) {
        bf16x8 bf = *(const bf16x8*)&brow[kk * 32];
        acc = mfma16(af[kk], bf, acc);
      }
      float bv = bp[sel][ntl * 16 + col];
#pragma unroll
      for (int r = 0; r < 4; r++)
        outp[sel][(rowbase + w * 16 + quad * 4 + r) * 64 + ntl * 16 + col] =
            f2bu((acc[r] + bv) * sc);
    }
  }
}

// Kernel 3a: partial l over one K-half. 64-q blocks (full MFMA density),
// grid 1024 = 8 b x 64 qt x 2 kh. Lp[(b*64+qt)*2+kh][64 q].
__global__ __launch_bounds__(256) void k_sumexp_l(
    const ushort* __restrict__ Qb, const ushort* __restrict__ Kb,
    float* __restrict__ Lp) {
  __shared__ float red[4][64];
  const int tid = threadIdx.x;
  const int b = blockIdx.x & 7;          // XCD swizzle: batch -> XCD
  const int rest = blockIdx.x >> 3;      // 0..127
  const int qt = rest & 63;
  const int kh = rest >> 6;              // K-half
  const int lane = tid & 63;
  const int w = tid >> 6;
  const int col = lane & 15;
  const int quad = lane >> 4;
  const size_t qbase = (size_t)b * 4096 + qt * 64;
  const size_t kbase = (size_t)b * 4096 + kh * 2048;
  bf16x8 af[4][2];
#pragma unroll
  for (int t = 0; t < 4; t++)
#pragma unroll
    for (int h = 0; h < 2; h++)
      af[t][h] = *(const bf16x8*)&Qb[(qbase + t * 16 + col) * 64 + quad * 8 + h * 32];
  const ushort* kp = &Kb[(kbase + w * 16 + col) * 64 + quad * 8];
  float lacc[4][4];
#pragma unroll
  for (int t = 0; t < 4; t++)
#pragma unroll
    for (int r = 0; r < 4; r++) lacc[t][r] = 0.f;
  bf16x8 nb0 = *(const bf16x8*)kp;
  bf16x8 nb1 = *(const bf16x8*)(kp + 32);
  for (int kt = 0; kt < 32; kt++) {
    bf16x8 b0 = nb0, b1 = nb1;
    if (kt < 31) {
      nb0 = *(const bf16x8*)(kp + (size_t)(kt + 1) * 4096);
      nb1 = *(const bf16x8*)(kp + (size_t)(kt + 1) * 4096 + 32);
    }
#pragma unroll
    for (int t = 0; t < 4; t++) {
      f32x4 acc = {0.f, 0.f, 0.f, 0.f};
      acc = mfma16(af[t][0], b0, acc);
      acc = mfma16(af[t][1], b1, acc);
#pragma unroll
      for (int r = 0; r < 4; r++) lacc[t][r] += fexp2(acc[r]);
    }
  }
#pragma unroll
  for (int t = 0; t < 4; t++)
#pragma unroll
    for (int r = 0; r < 4; r++) {
      float v = lacc[t][r];
      v += __shfl_xor(v, 1); v += __shfl_xor(v, 2);
      v += __shfl_xor(v, 4); v += __shfl_xor(v, 8);
      if (col == 0) red[w][t * 16 + quad * 4 + r] = v;
    }
  __syncthreads();
  if (tid < 64) {
    float l = red[0][tid] + red[1][tid] + red[2][tid] + red[3][tid];
    Lp[((size_t)(b * 64 + qt) * 2 + kh) * 64 + tid] = l;
  }
}

// Kernel 3b: combine K-half partials: Lo = lA+lB, Linv = 1/Lo.
__global__ __launch_bounds__(256) void k_lcomb(
    const float* __restrict__ Lp, float* __restrict__ Lo, float* __restrict__ Linv) {
  int i = blockIdx.x * 256 + threadIdx.x;   // 32768 = 8*64*64
  int bqt = i >> 6, q = i & 63;
  float l = Lp[(size_t)bqt * 128 + q] + Lp[(size_t)bqt * 128 + 64 + q];
  Lo[i] = l;         // layout (b*64+qt)*64+q == b*4096+qt*64+q
  Linv[i] = 1.f / l;
}

// Kernel 3c: IP sweep over one K-half. IP[b*64+qt][k] = sum_q E_qk/l_q.
__global__ __launch_bounds__(256) void k_sumexp_ip(
    const ushort* __restrict__ Qb, const ushort* __restrict__ Kb,
    const float* __restrict__ Linv, float* __restrict__ IP) {
  __shared__ float lred[64];
  const int tid = threadIdx.x;
  const int b = blockIdx.x & 7;
  const int rest = blockIdx.x >> 3;
  const int qt = rest & 63;
  const int kh = rest >> 6;
  const int lane = tid & 63;
  const int w = tid >> 6;
  const int col = lane & 15;
  const int quad = lane >> 4;
  const size_t qbase = (size_t)b * 4096 + qt * 64;
  const size_t kbase = (size_t)b * 4096 + kh * 2048;
  if (tid < 64) lred[tid] = Linv[qbase + tid];
  bf16x8 af[4][2];
#pragma unroll
  for (int t = 0; t < 4; t++)
#pragma unroll
    for (int h = 0; h < 2; h++)
      af[t][h] = *(const bf16x8*)&Qb[(qbase + t * 16 + col) * 64 + quad * 8 + h * 32];
  __syncthreads();
  float linv[4][4];
#pragma unroll
  for (int t = 0; t < 4; t++)
#pragma unroll
    for (int r = 0; r < 4; r++) linv[t][r] = lred[t * 16 + quad * 4 + r];
  const ushort* kp = &Kb[(kbase + w * 16 + col) * 64 + quad * 8];
  bf16x8 nb0 = *(const bf16x8*)kp;
  bf16x8 nb1 = *(const bf16x8*)(kp + 32);
  for (int kt = 0; kt < 32; kt++) {
    bf16x8 b0 = nb0, b1 = nb1;
    if (kt < 31) {
      nb0 = *(const bf16x8*)(kp + (size_t)(kt + 1) * 4096);
      nb1 = *(const bf16x8*)(kp + (size_t)(kt + 1) * 4096 + 32);
    }
    float ip = 0.f;
#pragma unroll
    for (int t = 0; t < 4; t++) {
      f32x4 acc = {0.f, 0.f, 0.f, 0.f};
      acc = mfma16(af[t][0], b0, acc);
      acc = mfma16(af[t][1], b1, acc);
#pragma unroll
      for (int r = 0; r < 4; r++) ip += fexp2(acc[r]) * linv[t][r];
    }
    ip += __shfl_xor(ip, 16);   // sum the 4 quad-groups (rows)
    ip += __shfl_xor(ip, 32);
    if (quad == 0)
      IP[((size_t)(b * 64 + qt)) * 4096 + (kh * 32 + kt) * 64 + w * 16 + col] = ip;
  }
}

// Kernel 4a: imp[b][k] = sum_r IP[b*64+r][k] (fixed r order -> deterministic).
__global__ __launch_bounds__(256) void k_impsum(
    const float* __restrict__ IP, float* __restrict__ imp) {
  const int tid = threadIdx.x;
  const int b = blockIdx.y;
  const int col = blockIdx.x * 256 + tid;
  const float* p = IP + (size_t)b * 64 * 4096 + col;
  float s = 0.f;
#pragma unroll 8
  for (int r = 0; r < 64; r++) s += p[(size_t)r * 4096];
  imp[(size_t)b * 4096 + col] = s;
}

// Kernel 4b: exact top-2048 by rank counting (matches lax.top_k ties) and
// rank-indexed gather into compacted Kc/Vc.
__global__ __launch_bounds__(256) void k_mask2c(
    const float* __restrict__ imp, const ushort* __restrict__ Kb,
    const ushort* __restrict__ Vb, ushort* __restrict__ Kc,
    ushort* __restrict__ Vc) {
  __shared__ __align__(16) float imps[4096];
  __shared__ int part[4][64];
  const int tid = threadIdx.x;
  const int b = blockIdx.y;
  const int base = blockIdx.x * 64;
  for (int i = tid; i < 4096; i += 256) imps[i] = imp[(size_t)b * 4096 + i];
  __syncthreads();
  const int cand = tid & 63;
  const int seg = tid >> 6;
  const int k = base + cand;
  const float v = imps[k];
  int cnt = 0;
  const int j0 = seg * 1024;
  for (int j = j0; j < j0 + 1024; j += 4) {
    float4 a = *(const float4*)&imps[j];
    cnt += (a.x > v) ? 1 : ((a.x == v && (j + 0) < k) ? 1 : 0);
    cnt += (a.y > v) ? 1 : ((a.y == v && (j + 1) < k) ? 1 : 0);
    cnt += (a.z > v) ? 1 : ((a.z == v && (j + 2) < k) ? 1 : 0);
    cnt += (a.w > v) ? 1 : ((a.w == v && (j + 3) < k) ? 1 : 0);
  }
  part[seg][cand] = cnt;
  __syncthreads();
  const int c = part[0][cand] + part[1][cand] + part[2][cand] + part[3][cand];
  if (c < 2048) {
    const ushort* ksrc = &Kb[((size_t)b * 4096 + k) * 64 + seg * 16];
    const ushort* vsrc = &Vb[((size_t)b * 4096 + k) * 64 + seg * 16];
    ushort* kdst = &Kc[((size_t)b * 2048 + c) * 64 + seg * 16];
    ushort* vdst = &Vc[((size_t)b * 2048 + c) * 64 + seg * 16];
    *(uint4*)kdst = *(const uint4*)ksrc;
    *(uint4*)(kdst + 8) = *(const uint4*)(ksrc + 8);
    *(uint4*)vdst = *(const uint4*)vsrc;
    *(uint4*)(vdst + 8) = *(const uint4*)(vsrc + 8);
  }
}

// Kernel 5: MFMA attention output + projection over COMPACTED keys (32 tiles).
__global__ __launch_bounds__(256) void k_attn_out(
    const ushort* __restrict__ Qb, const ushort* __restrict__ Kc,
    const ushort* __restrict__ Vc, const float* __restrict__ Lo,
    const float* __restrict__ owp, const float* __restrict__ obp,
    float* __restrict__ out) {
  __shared__ __align__(16) ushort Vt[64][72];   // V transposed: [c][k]
  __shared__ __align__(16) ushort Ps[64][72];   // P (then AO) in A-layout
  __shared__ __align__(16) ushort ows[64][72];  // ow bf16
  __shared__ float dred[4][64];
  __shared__ float lqs[64];
  const int tid = threadIdx.x;
  const int b = blockIdx.x & 7;
  const int qt = blockIdx.x >> 3;
  const int lane = tid & 63;
  const int w = tid >> 6;
  const int col = lane & 15;
  const int quad = lane >> 4;
  const size_t qbase = (size_t)b * 4096 + qt * 64;
  const size_t kbase = (size_t)b * 2048;   // compacted
  bf16x8 af[4][2];
#pragma unroll
  for (int t = 0; t < 4; t++)
#pragma unroll
    for (int h = 0; h < 2; h++)
      af[t][h] = *(const bf16x8*)&Qb[(qbase + t * 16 + col) * 64 + quad * 8 + h * 32];
  for (int i = tid; i < 4096; i += 256) ows[i >> 6][i & 63] = f2bu(owp[i]);
  if (tid < 64) lqs[tid] = Lo[qbase + tid];
  f32x4 pv[4];
  float dpacc[4][4];
#pragma unroll
  for (int t = 0; t < 4; t++) {
    pv[t] = (f32x4){0.f, 0.f, 0.f, 0.f};
#pragma unroll
    for (int r = 0; r < 4; r++) dpacc[t][r] = 0.f;
  }
  const int vrow = tid & 63;   // Vt staging: lane covers one V row,
  const int vch = tid >> 6;    // wave-indexed c-chunk -> conflict-free writes
  const ushort* kp = &Kc[(kbase + w * 16 + col) * 64 + quad * 8];
  bf16x8 nb0 = *(const bf16x8*)kp;
  bf16x8 nb1 = *(const bf16x8*)(kp + 32);
  for (int kt = 0; kt < 32; kt++) {
    __syncthreads();   // prev iteration done reading Vt/Ps
    {
      const ushort* vsrc = &Vc[(kbase + kt * 64 + vrow) * 64 + vch * 16];
      uint4 v0 = *(const uint4*)vsrc;
      uint4 v1 = *(const uint4*)(vsrc + 8);
      ushort tmp[16];
      *(uint4*)&tmp[0] = v0;
      *(uint4*)&tmp[8] = v1;
#pragma unroll
      for (int j = 0; j < 16; j++) Vt[vch * 16 + j][vrow] = tmp[j];
    }
    bf16x8 b0 = nb0, b1 = nb1;
    if (kt < 31) {
      nb0 = *(const bf16x8*)(kp + (size_t)(kt + 1) * 4096);
      nb1 = *(const bf16x8*)(kp + (size_t)(kt + 1) * 4096 + 32);
    }
#pragma unroll
    for (int t = 0; t < 4; t++) {
      f32x4 acc = {0.f, 0.f, 0.f, 0.f};
      acc = mfma16(af[t][0], b0, acc);
      acc = mfma16(af[t][1], b1, acc);
#pragma unroll
      for (int r = 0; r < 4; r++) {
        float p = fexp2(acc[r]);
        dpacc[t][r] += p;
        Ps[t * 16 + quad * 4 + r][w * 16 + col] = f2bu(p);
      }
    }
    __syncthreads();   // Vt + Ps visible
    bf16x8 v0f = *(const bf16x8*)&Vt[w * 16 + col][quad * 8];
    bf16x8 v1f = *(const bf16x8*)&Vt[w * 16 + col][quad * 8 + 32];
#pragma unroll
    for (int t = 0; t < 4; t++) {
      bf16x8 p0 = *(const bf16x8*)&Ps[t * 16 + col][quad * 8];
      bf16x8 p1 = *(const bf16x8*)&Ps[t * 16 + col][quad * 8 + 32];
      pv[t] = mfma16(p0, v0f, pv[t]);
      pv[t] = mfma16(p1, v1f, pv[t]);
    }
  }
  // den: reduce dpacc over the wave's 16 cols, then across waves
#pragma unroll
  for (int t = 0; t < 4; t++)
#pragma unroll
    for (int r = 0; r < 4; r++) {
      float v = dpacc[t][r];
      v += __shfl_xor(v, 1); v += __shfl_xor(v, 2);
      v += __shfl_xor(v, 4); v += __shfl_xor(v, 8);
      if (col == 0) dred[w][t * 16 + quad * 4 + r] = v;
    }
  __syncthreads();
  // normalize pv -> AO (bf16, A-layout in Ps)
#pragma unroll
  for (int t = 0; t < 4; t++)
#pragma unroll
    for (int r = 0; r < 4; r++) {
      int q = t * 16 + quad * 4 + r;
      float den = dred[0][q] + dred[1][q] + dred[2][q] + dred[3][q] + 1e-8f * lqs[q];
      Ps[q][w * 16 + col] = f2bu(pv[t][r] / den);
    }
  __syncthreads();
  // projection: out[q][co] = sum_c AO[q][c]*ow[co][c] + ob[co]
  bf16x8 w0 = *(const bf16x8*)&ows[w * 16 + col][quad * 8];
  bf16x8 w1 = *(const bf16x8*)&ows[w * 16 + col][quad * 8 + 32];
  const float obv = obp[w * 16 + col];
#pragma unroll
  for (int t = 0; t < 4; t++) {
    bf16x8 p0 = *(const bf16x8*)&Ps[t * 16 + col][quad * 8];
    bf16x8 p1 = *(const bf16x8*)&Ps[t * 16 + col][quad * 8 + 32];
    f32x4 oc = {0.f, 0.f, 0.f, 0.f};
    oc = mfma16(p0, w0, oc);
    oc = mfma16(p1, w1, oc);
#pragma unroll
    for (int r = 0; r < 4; r++) {
      int q = t * 16 + quad * 4 + r;
      int co = w * 16 + col;
      out[((size_t)(b * 64 + co)) * 4096 + qt * 64 + q] = oc[r] + obv;
    }
  }
}

extern "C" void kernel_launch(void* const* d_in, const int* in_sizes, int n_in,
                              void* d_out, int out_size, void* d_ws, size_t ws_size,
                              hipStream_t stream) {
  const float* x  = (const float*)d_in[0];
  const float* w1 = (const float*)d_in[1];
  const float* b1 = (const float*)d_in[2];
  const float* w3 = (const float*)d_in[3];
  const float* b3 = (const float*)d_in[4];
  const float* w5 = (const float*)d_in[5];
  const float* b5 = (const float*)d_in[6];
  const float* qw = (const float*)d_in[7];
  const float* qb = (const float*)d_in[8];
  const float* kw = (const float*)d_in[9];
  const float* kb = (const float*)d_in[10];
  const float* vw = (const float*)d_in[11];
  const float* vb = (const float*)d_in[12];
  const float* ow = (const float*)d_in[13];
  const float* ob = (const float*)d_in[14];
  float* out = (float*)d_out;
  float* ws = (float*)d_ws;
  // workspace layout (float units): ~38.5 MB total
  ushort* F    = (ushort*)ws;                 // 6,291,456 us = 3,145,728 f
  ushort* Qb   = (ushort*)(ws + 3145728);     // 1,048,576 f
  ushort* Kb   = (ushort*)(ws + 4194304);     // 1,048,576 f
  ushort* Vb   = (ushort*)(ws + 5242880);     // 1,048,576 f
  float*  Lo   = ws + 6291456;                // 32,768 f
  float*  Linv = ws + 6324224;                // 32,768 f
  float*  Lp   = ws + 6356992;                // 65,536 f
  float*  IP   = ws + 6422528;                // 2,097,152 f
  float*  imp  = ws + 8519680;                // 32,768 f
  ushort* Kc   = (ushort*)(ws + 8552448);     // 524,288 f
  ushort* Vc   = (ushort*)(ws + 9076736);     // 524,288 f
  ushort* Wb   = (ushort*)(ws + 9601024);     // 18,432 f

  k_w2b<<<144, 256, 0, stream>>>(qw, kw, vw, Wb);
  k_conv<<<dim3(64, 8), 256, 0, stream>>>(x, w1, b1, w3, b3, w5, b5, F);
  k_qkv<<<512, 256, 0, stream>>>(F, Wb, qb, kb, vb, Qb, Kb, Vb);
  k_sumexp_l<<<1024, 256, 0, stream>>>(Qb, Kb, Lp);
  k_lcomb<<<128, 256, 0, stream>>>(Lp, Lo, Linv);
  k_sumexp_ip<<<1024, 256, 0, stream>>>(Qb, Kb, Linv, IP);
  k_impsum<<<dim3(16, 8), 256, 0, stream>>>(IP, imp);
  k_mask2c<<<dim3(64, 8), 256, 0, stream>>>(imp, Kb, Vb, Kc, Vc);
  k_attn_out<<<512, 256, 0, stream>>>(Qb, Kc, Vc, Lo, ow, ob, out);
}

// Round 12
// 333.820 us; speedup vs baseline: 1.1386x; 1.0692x over previous
//
#include <hip/hip_runtime.h>
#include <hip/hip_bf16.h>

typedef unsigned short ushort;
typedef __bf16 bf16x8 __attribute__((ext_vector_type(8)));
typedef float f32x4 __attribute__((ext_vector_type(4)));

__device__ __forceinline__ ushort f2bu(float f) {
  __hip_bfloat16 h = __float2bfloat16(f);
  return *(ushort*)&h;
}
__device__ __forceinline__ f32x4 mfma16(bf16x8 a, bf16x8 b, f32x4 c) {
  return __builtin_amdgcn_mfma_f32_16x16x32_bf16(a, b, c, 0, 0, 0);
}
__device__ __forceinline__ float fexp2(float x) { return __builtin_amdgcn_exp2f(x); }

// ---------------------------------------------------------------------------
// Problem constants: B=8, C=64, E=64, H=W=64, N=4096, 3C=192, k_val=2048
// Inputs fp32 / output fp32 (proven round 3). All GEMMs on MFMA.
// Q pre-scaled by 0.125*log2(e): E = 2^score = exp(s/8), single v_exp.
// Round 12: K-split sumexp kept, but `#pragma unroll 1` on the 32-iter
// K-loops. Round 11's 32-iter loops crossed the compiler's full-unroll
// threshold -> 256 VGPR, 10% occupancy, ~49 MB scratch spill per dispatch.
// ---------------------------------------------------------------------------

// Kernel 1: f_flat[b][n][0:64]=1x1 conv, [64:128]=dw3x3, [128:192]=dw5x5
__global__ __launch_bounds__(256) void k_conv(
    const float* __restrict__ x, const float* __restrict__ w1, const float* __restrict__ b1,
    const float* __restrict__ w3, const float* __restrict__ b3,
    const float* __restrict__ w5, const float* __restrict__ b5,
    ushort* __restrict__ f) {
  __shared__ float xs[64][64];
  __shared__ float w1s[64 * 65];
  __shared__ float w3s[576];
  __shared__ float w5s[1600];
  __shared__ float bs1[64], bs3[64], bs5[64];
  const int tid = threadIdx.x;
  const int y = blockIdx.x;
  const int b = blockIdx.y;
  for (int i = tid; i < 4096; i += 256) {
    int ch = i >> 6, w = i & 63;
    xs[ch][w] = x[((size_t)(b * 64 + ch) * 64 + y) * 64 + w];
  }
  for (int i = tid; i < 4096; i += 256) w1s[(i >> 6) * 65 + (i & 63)] = w1[i];
  for (int i = tid; i < 576; i += 256) w3s[i] = w3[i];
  for (int i = tid; i < 1600; i += 256) w5s[i] = w5[i];
  if (tid < 64) { bs1[tid] = b1[tid]; bs3[tid] = b3[tid]; bs5[tid] = b5[tid]; }
  __syncthreads();
  const int px = tid & 63;
  const int cg = tid >> 6;
  const int cb = cg * 16;
  ushort* fo = f + ((size_t)b * 4096 + y * 64 + px) * 192;
  float a1[16];
#pragma unroll
  for (int j = 0; j < 16; j++) a1[j] = bs1[cb + j];
  for (int ic = 0; ic < 64; ic++) {
    float xv = xs[ic][px];
#pragma unroll
    for (int j = 0; j < 16; j++) a1[j] += w1s[(cb + j) * 65 + ic] * xv;
  }
#pragma unroll
  for (int j = 0; j < 16; j++) fo[cb + j] = f2bu(a1[j]);
#pragma unroll 4
  for (int j = 0; j < 16; j++) {
    int c = cb + j;
    const float* xc = x + (size_t)(b * 64 + c) * 4096;
    float a3 = bs3[c], a5 = bs5[c];
#pragma unroll
    for (int dy = 0; dy < 5; dy++) {
      int yy = y + dy - 2;
      if (yy < 0 || yy >= 64) continue;
      const float* xr = xc + yy * 64;
#pragma unroll
      for (int dx = 0; dx < 5; dx++) {
        int wx = px + dx - 2;
        float v = (wx >= 0 && wx < 64) ? xr[wx] : 0.f;
        a5 += w5s[c * 25 + dy * 5 + dx] * v;
        if (dy >= 1 && dy <= 3 && dx >= 1 && dx <= 3)
          a3 += w3s[c * 9 + (dy - 1) * 3 + (dx - 1)] * v;
      }
    }
    fo[64 + c] = f2bu(a3);
    fo[128 + c] = f2bu(a5);
  }
}

// Kernel 1b: convert qw/kw/vw fp32 -> contiguous bf16 buffer [3][64][192].
__global__ __launch_bounds__(256) void k_w2b(
    const float* __restrict__ qw, const float* __restrict__ kw,
    const float* __restrict__ vw, ushort* __restrict__ Wb) {
  int i = blockIdx.x * 256 + threadIdx.x;   // 36864 total
  const float* src = (i < 12288) ? qw : (i < 24576) ? kw : vw;
  int off = (i < 12288) ? i : (i < 24576) ? (i - 12288) : (i - 24576);
  Wb[i] = f2bu(src[off]);
}

// Kernel 2: Q/K/V = F @ {qw,kw,vw}^T + bias via MFMA. 64 rows/block, 4 waves.
// Q pre-scaled by 0.125*log2(e) (exp -> exp2 downstream).
__global__ __launch_bounds__(256) void k_qkv(
    const ushort* __restrict__ F, const ushort* __restrict__ Wb,
    const float* __restrict__ qb, const float* __restrict__ kb,
    const float* __restrict__ vb,
    ushort* __restrict__ Q, ushort* __restrict__ K, ushort* __restrict__ V) {
  __shared__ __align__(16) ushort fs[64][200];   // stride 200: even granule spread
  const int tid = threadIdx.x;
  const int w = tid >> 6;
  const int lane = tid & 63;
  const int col = lane & 15;
  const int quad = lane >> 4;
  const size_t rowbase = (size_t)blockIdx.x * 64;
  for (int i = tid; i < 1536; i += 256) {   // 16B chunks: 64*192*2/16
    int r = i / 24, c8 = i % 24;
    *(uint4*)&fs[r][c8 * 8] = *(const uint4*)&F[rowbase * 192 + (size_t)i * 8];
  }
  __syncthreads();
  bf16x8 af[6];
#pragma unroll
  for (int kk = 0; kk < 6; kk++)
    af[kk] = *(const bf16x8*)&fs[w * 16 + col][kk * 32 + quad * 8];
  ushort* const outp[3] = {Q, K, V};
  const float* const bp[3] = {qb, kb, vb};
#pragma unroll
  for (int sel = 0; sel < 3; sel++) {
    const ushort* wsel = Wb + sel * 12288;
    const float sc = (sel == 0) ? 0.125f * 1.44269504088896f : 1.0f;
#pragma unroll
    for (int ntl = 0; ntl < 4; ntl++) {
      const ushort* brow = wsel + (ntl * 16 + col) * 192 + quad * 8;
      f32x4 acc = {0.f, 0.f, 0.f, 0.f};
#pragma unroll
      for (int kk = 0; kk < 6; kk++) {
        bf16x8 bf = *(const bf16x8*)&brow[kk * 32];
        acc = mfma16(af[kk], bf, acc);
      }
      float bv = bp[sel][ntl * 16 + col];
#pragma unroll
      for (int r = 0; r < 4; r++)
        outp[sel][(rowbase + w * 16 + quad * 4 + r) * 64 + ntl * 16 + col] =
            f2bu((acc[r] + bv) * sc);
    }
  }
}

// Kernel 3a: partial l over one K-half. 64-q blocks (full MFMA density),
// grid 1024 = 8 b x 64 qt x 2 kh. Lp[(b*64+qt)*2+kh][64 q].
__global__ __launch_bounds__(256) void k_sumexp_l(
    const ushort* __restrict__ Qb, const ushort* __restrict__ Kb,
    float* __restrict__ Lp) {
  __shared__ float red[4][64];
  const int tid = threadIdx.x;
  const int b = blockIdx.x & 7;          // XCD swizzle: batch -> XCD
  const int rest = blockIdx.x >> 3;      // 0..127
  const int qt = rest & 63;
  const int kh = rest >> 6;              // K-half
  const int lane = tid & 63;
  const int w = tid >> 6;
  const int col = lane & 15;
  const int quad = lane >> 4;
  const size_t qbase = (size_t)b * 4096 + qt * 64;
  const size_t kbase = (size_t)b * 4096 + kh * 2048;
  bf16x8 af[4][2];
#pragma unroll
  for (int t = 0; t < 4; t++)
#pragma unroll
    for (int h = 0; h < 2; h++)
      af[t][h] = *(const bf16x8*)&Qb[(qbase + t * 16 + col) * 64 + quad * 8 + h * 32];
  const ushort* kp = &Kb[(kbase + w * 16 + col) * 64 + quad * 8];
  float lacc[4][4];
#pragma unroll
  for (int t = 0; t < 4; t++)
#pragma unroll
    for (int r = 0; r < 4; r++) lacc[t][r] = 0.f;
  bf16x8 nb0 = *(const bf16x8*)kp;
  bf16x8 nb1 = *(const bf16x8*)(kp + 32);
#pragma unroll 1   // rolled: round 11's full unroll -> 256 VGPR + scratch spill
  for (int kt = 0; kt < 32; kt++) {
    bf16x8 b0 = nb0, b1 = nb1;
    if (kt < 31) {
      nb0 = *(const bf16x8*)(kp + (size_t)(kt + 1) * 4096);
      nb1 = *(const bf16x8*)(kp + (size_t)(kt + 1) * 4096 + 32);
    }
#pragma unroll
    for (int t = 0; t < 4; t++) {
      f32x4 acc = {0.f, 0.f, 0.f, 0.f};
      acc = mfma16(af[t][0], b0, acc);
      acc = mfma16(af[t][1], b1, acc);
#pragma unroll
      for (int r = 0; r < 4; r++) lacc[t][r] += fexp2(acc[r]);
    }
  }
#pragma unroll
  for (int t = 0; t < 4; t++)
#pragma unroll
    for (int r = 0; r < 4; r++) {
      float v = lacc[t][r];
      v += __shfl_xor(v, 1); v += __shfl_xor(v, 2);
      v += __shfl_xor(v, 4); v += __shfl_xor(v, 8);
      if (col == 0) red[w][t * 16 + quad * 4 + r] = v;
    }
  __syncthreads();
  if (tid < 64) {
    float l = red[0][tid] + red[1][tid] + red[2][tid] + red[3][tid];
    Lp[((size_t)(b * 64 + qt) * 2 + kh) * 64 + tid] = l;
  }
}

// Kernel 3b: combine K-half partials: Lo = lA+lB, Linv = 1/Lo.
__global__ __launch_bounds__(256) void k_lcomb(
    const float* __restrict__ Lp, float* __restrict__ Lo, float* __restrict__ Linv) {
  int i = blockIdx.x * 256 + threadIdx.x;   // 32768 = 8*64*64
  int bqt = i >> 6, q = i & 63;
  float l = Lp[(size_t)bqt * 128 + q] + Lp[(size_t)bqt * 128 + 64 + q];
  Lo[i] = l;         // layout (b*64+qt)*64+q == b*4096+qt*64+q
  Linv[i] = 1.f / l;
}

// Kernel 3c: IP sweep over one K-half. IP[b*64+qt][k] = sum_q E_qk/l_q.
__global__ __launch_bounds__(256) void k_sumexp_ip(
    const ushort* __restrict__ Qb, const ushort* __restrict__ Kb,
    const float* __restrict__ Linv, float* __restrict__ IP) {
  __shared__ float lred[64];
  const int tid = threadIdx.x;
  const int b = blockIdx.x & 7;
  const int rest = blockIdx.x >> 3;
  const int qt = rest & 63;
  const int kh = rest >> 6;
  const int lane = tid & 63;
  const int w = tid >> 6;
  const int col = lane & 15;
  const int quad = lane >> 4;
  const size_t qbase = (size_t)b * 4096 + qt * 64;
  const size_t kbase = (size_t)b * 4096 + kh * 2048;
  if (tid < 64) lred[tid] = Linv[qbase + tid];
  bf16x8 af[4][2];
#pragma unroll
  for (int t = 0; t < 4; t++)
#pragma unroll
    for (int h = 0; h < 2; h++)
      af[t][h] = *(const bf16x8*)&Qb[(qbase + t * 16 + col) * 64 + quad * 8 + h * 32];
  __syncthreads();
  float linv[4][4];
#pragma unroll
  for (int t = 0; t < 4; t++)
#pragma unroll
    for (int r = 0; r < 4; r++) linv[t][r] = lred[t * 16 + quad * 4 + r];
  const ushort* kp = &Kb[(kbase + w * 16 + col) * 64 + quad * 8];
  bf16x8 nb0 = *(const bf16x8*)kp;
  bf16x8 nb1 = *(const bf16x8*)(kp + 32);
#pragma unroll 1   // rolled: see k_sumexp_l note
  for (int kt = 0; kt < 32; kt++) {
    bf16x8 b0 = nb0, b1 = nb1;
    if (kt < 31) {
      nb0 = *(const bf16x8*)(kp + (size_t)(kt + 1) * 4096);
      nb1 = *(const bf16x8*)(kp + (size_t)(kt + 1) * 4096 + 32);
    }
    float ip = 0.f;
#pragma unroll
    for (int t = 0; t < 4; t++) {
      f32x4 acc = {0.f, 0.f, 0.f, 0.f};
      acc = mfma16(af[t][0], b0, acc);
      acc = mfma16(af[t][1], b1, acc);
#pragma unroll
      for (int r = 0; r < 4; r++) ip += fexp2(acc[r]) * linv[t][r];
    }
    ip += __shfl_xor(ip, 16);   // sum the 4 quad-groups (rows)
    ip += __shfl_xor(ip, 32);
    if (quad == 0)
      IP[((size_t)(b * 64 + qt)) * 4096 + (kh * 32 + kt) * 64 + w * 16 + col] = ip;
  }
}

// Kernel 4a: imp[b][k] = sum_r IP[b*64+r][k] (fixed r order -> deterministic).
__global__ __launch_bounds__(256) void k_impsum(
    const float* __restrict__ IP, float* __restrict__ imp) {
  const int tid = threadIdx.x;
  const int b = blockIdx.y;
  const int col = blockIdx.x * 256 + tid;
  const float* p = IP + (size_t)b * 64 * 4096 + col;
  float s = 0.f;
#pragma unroll 8
  for (int r = 0; r < 64; r++) s += p[(size_t)r * 4096];
  imp[(size_t)b * 4096 + col] = s;
}

// Kernel 4b: exact top-2048 by rank counting (matches lax.top_k ties) and
// rank-indexed gather into compacted Kc/Vc.
__global__ __launch_bounds__(256) void k_mask2c(
    const float* __restrict__ imp, const ushort* __restrict__ Kb,
    const ushort* __restrict__ Vb, ushort* __restrict__ Kc,
    ushort* __restrict__ Vc) {
  __shared__ __align__(16) float imps[4096];
  __shared__ int part[4][64];
  const int tid = threadIdx.x;
  const int b = blockIdx.y;
  const int base = blockIdx.x * 64;
  for (int i = tid; i < 4096; i += 256) imps[i] = imp[(size_t)b * 4096 + i];
  __syncthreads();
  const int cand = tid & 63;
  const int seg = tid >> 6;
  const int k = base + cand;
  const float v = imps[k];
  int cnt = 0;
  const int j0 = seg * 1024;
  for (int j = j0; j < j0 + 1024; j += 4) {
    float4 a = *(const float4*)&imps[j];
    cnt += (a.x > v) ? 1 : ((a.x == v && (j + 0) < k) ? 1 : 0);
    cnt += (a.y > v) ? 1 : ((a.y == v && (j + 1) < k) ? 1 : 0);
    cnt += (a.z > v) ? 1 : ((a.z == v && (j + 2) < k) ? 1 : 0);
    cnt += (a.w > v) ? 1 : ((a.w == v && (j + 3) < k) ? 1 : 0);
  }
  part[seg][cand] = cnt;
  __syncthreads();
  const int c = part[0][cand] + part[1][cand] + part[2][cand] + part[3][cand];
  if (c < 2048) {
    const ushort* ksrc = &Kb[((size_t)b * 4096 + k) * 64 + seg * 16];
    const ushort* vsrc = &Vb[((size_t)b * 4096 + k) * 64 + seg * 16];
    ushort* kdst = &Kc[((size_t)b * 2048 + c) * 64 + seg * 16];
    ushort* vdst = &Vc[((size_t)b * 2048 + c) * 64 + seg * 16];
    *(uint4*)kdst = *(const uint4*)ksrc;
    *(uint4*)(kdst + 8) = *(const uint4*)(ksrc + 8);
    *(uint4*)vdst = *(const uint4*)vsrc;
    *(uint4*)(vdst + 8) = *(const uint4*)(vsrc + 8);
  }
}

// Kernel 5: MFMA attention output + projection over COMPACTED keys (32 tiles).
__global__ __launch_bounds__(256) void k_attn_out(
    const ushort* __restrict__ Qb, const ushort* __restrict__ Kc,
    const ushort* __restrict__ Vc, const float* __restrict__ Lo,
    const float* __restrict__ owp, const float* __restrict__ obp,
    float* __restrict__ out) {
  __shared__ __align__(16) ushort Vt[64][72];   // V transposed: [c][k]
  __shared__ __align__(16) ushort Ps[64][72];   // P (then AO) in A-layout
  __shared__ __align__(16) ushort ows[64][72];  // ow bf16
  __shared__ float dred[4][64];
  __shared__ float lqs[64];
  const int tid = threadIdx.x;
  const int b = blockIdx.x & 7;
  const int qt = blockIdx.x >> 3;
  const int lane = tid & 63;
  const int w = tid >> 6;
  const int col = lane & 15;
  const int quad = lane >> 4;
  const size_t qbase = (size_t)b * 4096 + qt * 64;
  const size_t kbase = (size_t)b * 2048;   // compacted
  bf16x8 af[4][2];
#pragma unroll
  for (int t = 0; t < 4; t++)
#pragma unroll
    for (int h = 0; h < 2; h++)
      af[t][h] = *(const bf16x8*)&Qb[(qbase + t * 16 + col) * 64 + quad * 8 + h * 32];
  for (int i = tid; i < 4096; i += 256) ows[i >> 6][i & 63] = f2bu(owp[i]);
  if (tid < 64) lqs[tid] = Lo[qbase + tid];
  f32x4 pv[4];
  float dpacc[4][4];
#pragma unroll
  for (int t = 0; t < 4; t++) {
    pv[t] = (f32x4){0.f, 0.f, 0.f, 0.f};
#pragma unroll
    for (int r = 0; r < 4; r++) dpacc[t][r] = 0.f;
  }
  const int vrow = tid & 63;   // Vt staging: lane covers one V row,
  const int vch = tid >> 6;    // wave-indexed c-chunk -> conflict-free writes
  const ushort* kp = &Kc[(kbase + w * 16 + col) * 64 + quad * 8];
  bf16x8 nb0 = *(const bf16x8*)kp;
  bf16x8 nb1 = *(const bf16x8*)(kp + 32);
  for (int kt = 0; kt < 32; kt++) {
    __syncthreads();   // prev iteration done reading Vt/Ps
    {
      const ushort* vsrc = &Vc[(kbase + kt * 64 + vrow) * 64 + vch * 16];
      uint4 v0 = *(const uint4*)vsrc;
      uint4 v1 = *(const uint4*)(vsrc + 8);
      ushort tmp[16];
      *(uint4*)&tmp[0] = v0;
      *(uint4*)&tmp[8] = v1;
#pragma unroll
      for (int j = 0; j < 16; j++) Vt[vch * 16 + j][vrow] = tmp[j];
    }
    bf16x8 b0 = nb0, b1 = nb1;
    if (kt < 31) {
      nb0 = *(const bf16x8*)(kp + (size_t)(kt + 1) * 4096);
      nb1 = *(const bf16x8*)(kp + (size_t)(kt + 1) * 4096 + 32);
    }
#pragma unroll
    for (int t = 0; t < 4; t++) {
      f32x4 acc = {0.f, 0.f, 0.f, 0.f};
      acc = mfma16(af[t][0], b0, acc);
      acc = mfma16(af[t][1], b1, acc);
#pragma unroll
      for (int r = 0; r < 4; r++) {
        float p = fexp2(acc[r]);
        dpacc[t][r] += p;
        Ps[t * 16 + quad * 4 + r][w * 16 + col] = f2bu(p);
      }
    }
    __syncthreads();   // Vt + Ps visible
    bf16x8 v0f = *(const bf16x8*)&Vt[w * 16 + col][quad * 8];
    bf16x8 v1f = *(const bf16x8*)&Vt[w * 16 + col][quad * 8 + 32];
#pragma unroll
    for (int t = 0; t < 4; t++) {
      bf16x8 p0 = *(const bf16x8*)&Ps[t * 16 + col][quad * 8];
      bf16x8 p1 = *(const bf16x8*)&Ps[t * 16 + col][quad * 8 + 32];
      pv[t] = mfma16(p0, v0f, pv[t]);
      pv[t] = mfma16(p1, v1f, pv[t]);
    }
  }
  // den: reduce dpacc over the wave's 16 cols, then across waves
#pragma unroll
  for (int t = 0; t < 4; t++)
#pragma unroll
    for (int r = 0; r < 4; r++) {
      float v = dpacc[t][r];
      v += __shfl_xor(v, 1); v += __shfl_xor(v, 2);
      v += __shfl_xor(v, 4); v += __shfl_xor(v, 8);
      if (col == 0) dred[w][t * 16 + quad * 4 + r] = v;
    }
  __syncthreads();
  // normalize pv -> AO (bf16, A-layout in Ps)
#pragma unroll
  for (int t = 0; t < 4; t++)
#pragma unroll
    for (int r = 0; r < 4; r++) {
      int q = t * 16 + quad * 4 + r;
      float den = dred[0][q] + dred[1][q] + dred[2][q] + dred[3][q] + 1e-8f * lqs[q];
      Ps[q][w * 16 + col] = f2bu(pv[t][r] / den);
    }
  __syncthreads();
  // projection: out[q][co] = sum_c AO[q][c]*ow[co][c] + ob[co]
  bf16x8 w0 = *(const bf16x8*)&ows[w * 16 + col][quad * 8];
  bf16x8 w1 = *(const bf16x8*)&ows[w * 16 + col][quad * 8 + 32];
  const float obv = obp[w * 16 + col];
#pragma unroll
  for (int t = 0; t < 4; t++) {
    bf16x8 p0 = *(const bf16x8*)&Ps[t * 16 + col][quad * 8];
    bf16x8 p1 = *(const bf16x8*)&Ps[t * 16 + col][quad * 8 + 32];
    f32x4 oc = {0.f, 0.f, 0.f, 0.f};
    oc = mfma16(p0, w0, oc);
    oc = mfma16(p1, w1, oc);
#pragma unroll
    for (int r = 0; r < 4; r++) {
      int q = t * 16 + quad * 4 + r;
      int co = w * 16 + col;
      out[((size_t)(b * 64 + co)) * 4096 + qt * 64 + q] = oc[r] + obv;
    }
  }
}

extern "C" void kernel_launch(void* const* d_in, const int* in_sizes, int n_in,
                              void* d_out, int out_size, void* d_ws, size_t ws_size,
                              hipStream_t stream) {
  const float* x  = (const float*)d_in[0];
  const float* w1 = (const float*)d_in[1];
  const float* b1 = (const float*)d_in[2];
  const float* w3 = (const float*)d_in[3];
  const float* b3 = (const float*)d_in[4];
  const float* w5 = (const float*)d_in[5];
  const float* b5 = (const float*)d_in[6];
  const float* qw = (const float*)d_in[7];
  const float* qb = (const float*)d_in[8];
  const float* kw = (const float*)d_in[9];
  const float* kb = (const float*)d_in[10];
  const float* vw = (const float*)d_in[11];
  const float* vb = (const float*)d_in[12];
  const float* ow = (const float*)d_in[13];
  const float* ob = (const float*)d_in[14];
  float* out = (float*)d_out;
  float* ws = (float*)d_ws;
  // workspace layout (float units): ~38.5 MB total
  ushort* F    = (ushort*)ws;                 // 6,291,456 us = 3,145,728 f
  ushort* Qb   = (ushort*)(ws + 3145728);     // 1,048,576 f
  ushort* Kb   = (ushort*)(ws + 4194304);     // 1,048,576 f
  ushort* Vb   = (ushort*)(ws + 5242880);     // 1,048,576 f
  float*  Lo   = ws + 6291456;                // 32,768 f
  float*  Linv = ws + 6324224;                // 32,768 f
  float*  Lp   = ws + 6356992;                // 65,536 f
  float*  IP   = ws + 6422528;                // 2,097,152 f
  float*  imp  = ws + 8519680;                // 32,768 f
  ushort* Kc   = (ushort*)(ws + 8552448);     // 524,288 f
  ushort* Vc   = (ushort*)(ws + 9076736);     // 524,288 f
  ushort* Wb   = (ushort*)(ws + 9601024);     // 18,432 f

  k_w2b<<<144, 256, 0, stream>>>(qw, kw, vw, Wb);
  k_conv<<<dim3(64, 8), 256, 0, stream>>>(x, w1, b1, w3, b3, w5, b5, F);
  k_qkv<<<512, 256, 0, stream>>>(F, Wb, qb, kb, vb, Qb, Kb, Vb);
  k_sumexp_l<<<1024, 256, 0, stream>>>(Qb, Kb, Lp);
  k_lcomb<<<128, 256, 0, stream>>>(Lp, Lo, Linv);
  k_sumexp_ip<<<1024, 256, 0, stream>>>(Qb, Kb, Linv, IP);
  k_impsum<<<dim3(16, 8), 256, 0, stream>>>(IP, imp);
  k_mask2c<<<dim3(64, 8), 256, 0, stream>>>(imp, Kb, Vb, Kc, Vc);
  k_attn_out<<<512, 256, 0, stream>>>(Qb, Kc, Vc, Lo, ow, ob, out);
}

// Round 13
// 306.421 us; speedup vs baseline: 1.2404x; 1.0894x over previous
//
#include <hip/hip_runtime.h>
#include <hip/hip_bf16.h>

typedef unsigned short ushort;
typedef __bf16 bf16x8 __attribute__((ext_vector_type(8)));
typedef float f32x4 __attribute__((ext_vector_type(4)));

__device__ __forceinline__ ushort f2bu(float f) {
  __hip_bfloat16 h = __float2bfloat16(f);
  return *(ushort*)&h;
}
__device__ __forceinline__ float bu2f(ushort u) {
  unsigned int v = ((unsigned int)u) << 16;
  return __uint_as_float(v);
}
__device__ __forceinline__ f32x4 mfma16(bf16x8 a, bf16x8 b, f32x4 c) {
  return __builtin_amdgcn_mfma_f32_16x16x32_bf16(a, b, c, 0, 0, 0);
}
__device__ __forceinline__ float fexp2(float x) { return __builtin_amdgcn_exp2f(x); }

// ---------------------------------------------------------------------------
// Problem constants: B=8, C=64, E=64, H=W=64, N=4096, 3C=192, k_val=2048
// Inputs fp32 / output fp32 (proven round 3). All GEMMs on MFMA.
// Q pre-scaled by 0.125*log2(e): E = 2^score = exp(s/8), single v_exp.
// Round 13: k_conv rewrite — x staged once as bf16 in LDS (zero-padded, no
// bounds checks); weights via wave-uniform s_load (readfirstlane) instead of
// per-FMA LDS broadcast reads (round 12's k_conv: ~1600 ds_read/thread).
// ---------------------------------------------------------------------------

// Kernel 1: f_flat[b][n][0:64]=1x1 conv, [64:128]=dw3x3, [128:192]=dw5x5
__global__ __launch_bounds__(256) void k_conv(
    const float* __restrict__ x, const float* __restrict__ w1t, const float* __restrict__ b1,
    const float* __restrict__ w3, const float* __restrict__ b3,
    const float* __restrict__ w5, const float* __restrict__ b5,
    ushort* __restrict__ f) {
  __shared__ ushort Xs[5 * 64 * 74];   // bf16 rows y-2..y+2, data cols 4..67
  const int tid = threadIdx.x;
  const int y = blockIdx.x;
  const int b = blockIdx.y;
  // zero the pad columns (0..3 and 68..73) of all 320 rows
  for (int i = tid; i < 320 * 5; i += 256) {
    int r = i / 5, pp = i % 5;
    int col = (pp < 2) ? 2 * pp : 68 + 2 * (pp - 2);
    *(unsigned int*)&Xs[r * 74 + col] = 0u;
  }
  // stage 5 rows x 64 ch x 64 px (fp32 global -> bf16 LDS), zeros at y-edges
#pragma unroll
  for (int k = 0; k < 20; k++) {
    int idx = tid + k * 256;           // 0..5119
    int px4 = idx & 15, ch = (idx >> 4) & 63, yy = idx >> 10;
    int ysrc = y + yy - 2;
    float4 v = make_float4(0.f, 0.f, 0.f, 0.f);
    if (ysrc >= 0 && ysrc < 64)
      v = *(const float4*)&x[(((size_t)(b * 64 + ch) * 64) + ysrc) * 64 + px4 * 4];
    unsigned int lo = (unsigned int)f2bu(v.x) | ((unsigned int)f2bu(v.y) << 16);
    unsigned int hi = (unsigned int)f2bu(v.z) | ((unsigned int)f2bu(v.w) << 16);
    int base = (yy * 64 + ch) * 74 + 4 + px4 * 4;
    *(unsigned int*)&Xs[base] = lo;
    *(unsigned int*)&Xs[base + 2] = hi;
  }
  __syncthreads();
  const int px = tid & 63;
  const int cbu = __builtin_amdgcn_readfirstlane((tid >> 6) * 16);  // wave-uniform
  ushort* fo = f + ((size_t)b * 4096 + y * 64 + px) * 192;
  // 1x1 conv: weights via scalar loads (w1t rows contiguous), x from LDS bf16
  float a1[16];
#pragma unroll
  for (int j = 0; j < 16; j++) a1[j] = b1[cbu + j];
  for (int ic = 0; ic < 64; ic++) {
    float xv = bu2f(Xs[(2 * 64 + ic) * 74 + 4 + px]);
    const float* wrow = &w1t[ic * 64 + cbu];   // 16 contiguous -> s_load_dwordx16
#pragma unroll
    for (int j = 0; j < 16; j++) a1[j] += wrow[j] * xv;
  }
#pragma unroll
  for (int j = 0; j < 16; j++) fo[cbu + j] = f2bu(a1[j]);
  // depthwise 3x3 + 5x5 from LDS (zero-padded -> no bounds checks)
#pragma unroll 4
  for (int j = 0; j < 16; j++) {
    int c = cbu + j;
    float a3 = b3[c], a5 = b5[c];
#pragma unroll
    for (int dy = 0; dy < 5; dy++) {
      const ushort* row = &Xs[(dy * 64 + c) * 74 + 2 + px];
#pragma unroll
      for (int dx = 0; dx < 5; dx++) {
        float v = bu2f(row[dx]);
        a5 += w5[c * 25 + dy * 5 + dx] * v;
        if (dy >= 1 && dy <= 3 && dx >= 1 && dx <= 3)
          a3 += w3[c * 9 + (dy - 1) * 3 + (dx - 1)] * v;
      }
    }
    fo[64 + c] = f2bu(a3);
    fo[128 + c] = f2bu(a5);
  }
}

// Kernel 1b: qw/kw/vw fp32 -> bf16 buffer [3][64][192]; w1 -> w1t (fp32, T).
__global__ __launch_bounds__(256) void k_w2b(
    const float* __restrict__ qw, const float* __restrict__ kw,
    const float* __restrict__ vw, const float* __restrict__ w1,
    ushort* __restrict__ Wb, float* __restrict__ w1t) {
  int i = blockIdx.x * 256 + threadIdx.x;   // 36864 + 4096 total
  if (i < 36864) {
    const float* src = (i < 12288) ? qw : (i < 24576) ? kw : vw;
    int off = (i < 12288) ? i : (i < 24576) ? (i - 12288) : (i - 24576);
    Wb[i] = f2bu(src[off]);
  } else {
    int j = i - 36864;
    if (j < 4096) w1t[(j & 63) * 64 + (j >> 6)] = w1[j];
  }
}

// Kernel 2: Q/K/V = F @ {qw,kw,vw}^T + bias via MFMA. 64 rows/block, 4 waves.
// Q pre-scaled by 0.125*log2(e) (exp -> exp2 downstream).
__global__ __launch_bounds__(256) void k_qkv(
    const ushort* __restrict__ F, const ushort* __restrict__ Wb,
    const float* __restrict__ qb, const float* __restrict__ kb,
    const float* __restrict__ vb,
    ushort* __restrict__ Q, ushort* __restrict__ K, ushort* __restrict__ V) {
  __shared__ __align__(16) ushort fs[64][200];   // stride 200: even granule spread
  const int tid = threadIdx.x;
  const int w = tid >> 6;
  const int lane = tid & 63;
  const int col = lane & 15;
  const int quad = lane >> 4;
  const size_t rowbase = (size_t)blockIdx.x * 64;
  for (int i = tid; i < 1536; i += 256) {   // 16B chunks: 64*192*2/16
    int r = i / 24, c8 = i % 24;
    *(uint4*)&fs[r][c8 * 8] = *(const uint4*)&F[rowbase * 192 + (size_t)i * 8];
  }
  __syncthreads();
  bf16x8 af[6];
#pragma unroll
  for (int kk = 0; kk < 6; kk++)
    af[kk] = *(const bf16x8*)&fs[w * 16 + col][kk * 32 + quad * 8];
  ushort* const outp[3] = {Q, K, V};
  const float* const bp[3] = {qb, kb, vb};
#pragma unroll
  for (int sel = 0; sel < 3; sel++) {
    const ushort* wsel = Wb + sel * 12288;
    const float sc = (sel == 0) ? 0.125f * 1.44269504088896f : 1.0f;
#pragma unroll
    for (int ntl = 0; ntl < 4; ntl++) {
      const ushort* brow = wsel + (ntl * 16 + col) * 192 + quad * 8;
      f32x4 acc = {0.f, 0.f, 0.f, 0.f};
#pragma unroll
      for (int kk = 0; kk < 6; kk++) {
        bf16x8 bf = *(const bf16x8*)&brow[kk * 32];
        acc = mfma16(af[kk], bf, acc);
      }
      float bv = bp[sel][ntl * 16 + col];
#pragma unroll
      for (int r = 0; r < 4; r++)
        outp[sel][(rowbase + w * 16 + quad * 4 + r) * 64 + ntl * 16 + col] =
            f2bu((acc[r] + bv) * sc);
    }
  }
}

// Kernel 3a: partial l over one K-half. 64-q blocks (full MFMA density),
// grid 1024 = 8 b x 64 qt x 2 kh. Lp[(b*64+qt)*2+kh][64 q].
__global__ __launch_bounds__(256) void k_sumexp_l(
    const ushort* __restrict__ Qb, const ushort* __restrict__ Kb,
    float* __restrict__ Lp) {
  __shared__ float red[4][64];
  const int tid = threadIdx.x;
  const int b = blockIdx.x & 7;          // XCD swizzle: batch -> XCD
  const int rest = blockIdx.x >> 3;      // 0..127
  const int qt = rest & 63;
  const int kh = rest >> 6;              // K-half
  const int lane = tid & 63;
  const int w = tid >> 6;
  const int col = lane & 15;
  const int quad = lane >> 4;
  const size_t qbase = (size_t)b * 4096 + qt * 64;
  const size_t kbase = (size_t)b * 4096 + kh * 2048;
  bf16x8 af[4][2];
#pragma unroll
  for (int t = 0; t < 4; t++)
#pragma unroll
    for (int h = 0; h < 2; h++)
      af[t][h] = *(const bf16x8*)&Qb[(qbase + t * 16 + col) * 64 + quad * 8 + h * 32];
  const ushort* kp = &Kb[(kbase + w * 16 + col) * 64 + quad * 8];
  float lacc[4][4];
#pragma unroll
  for (int t = 0; t < 4; t++)
#pragma unroll
    for (int r = 0; r < 4; r++) lacc[t][r] = 0.f;
  bf16x8 nb0 = *(const bf16x8*)kp;
  bf16x8 nb1 = *(const bf16x8*)(kp + 32);
#pragma unroll 1   // rolled: full unroll -> 256 VGPR + scratch spill (round 11)
  for (int kt = 0; kt < 32; kt++) {
    bf16x8 b0 = nb0, b1 = nb1;
    if (kt < 31) {
      nb0 = *(const bf16x8*)(kp + (size_t)(kt + 1) * 4096);
      nb1 = *(const bf16x8*)(kp + (size_t)(kt + 1) * 4096 + 32);
    }
#pragma unroll
    for (int t = 0; t < 4; t++) {
      f32x4 acc = {0.f, 0.f, 0.f, 0.f};
      acc = mfma16(af[t][0], b0, acc);
      acc = mfma16(af[t][1], b1, acc);
#pragma unroll
      for (int r = 0; r < 4; r++) lacc[t][r] += fexp2(acc[r]);
    }
  }
#pragma unroll
  for (int t = 0; t < 4; t++)
#pragma unroll
    for (int r = 0; r < 4; r++) {
      float v = lacc[t][r];
      v += __shfl_xor(v, 1); v += __shfl_xor(v, 2);
      v += __shfl_xor(v, 4); v += __shfl_xor(v, 8);
      if (col == 0) red[w][t * 16 + quad * 4 + r] = v;
    }
  __syncthreads();
  if (tid < 64) {
    float l = red[0][tid] + red[1][tid] + red[2][tid] + red[3][tid];
    Lp[((size_t)(b * 64 + qt) * 2 + kh) * 64 + tid] = l;
  }
}

// Kernel 3b: combine K-half partials: Lo = lA+lB, Linv = 1/Lo.
__global__ __launch_bounds__(256) void k_lcomb(
    const float* __restrict__ Lp, float* __restrict__ Lo, float* __restrict__ Linv) {
  int i = blockIdx.x * 256 + threadIdx.x;   // 32768 = 8*64*64
  int bqt = i >> 6, q = i & 63;
  float l = Lp[(size_t)bqt * 128 + q] + Lp[(size_t)bqt * 128 + 64 + q];
  Lo[i] = l;         // layout (b*64+qt)*64+q == b*4096+qt*64+q
  Linv[i] = 1.f / l;
}

// Kernel 3c: IP sweep over one K-half. IP[b*64+qt][k] = sum_q E_qk/l_q.
__global__ __launch_bounds__(256) void k_sumexp_ip(
    const ushort* __restrict__ Qb, const ushort* __restrict__ Kb,
    const float* __restrict__ Linv, float* __restrict__ IP) {
  __shared__ float lred[64];
  const int tid = threadIdx.x;
  const int b = blockIdx.x & 7;
  const int rest = blockIdx.x >> 3;
  const int qt = rest & 63;
  const int kh = rest >> 6;
  const int lane = tid & 63;
  const int w = tid >> 6;
  const int col = lane & 15;
  const int quad = lane >> 4;
  const size_t qbase = (size_t)b * 4096 + qt * 64;
  const size_t kbase = (size_t)b * 4096 + kh * 2048;
  if (tid < 64) lred[tid] = Linv[qbase + tid];
  bf16x8 af[4][2];
#pragma unroll
  for (int t = 0; t < 4; t++)
#pragma unroll
    for (int h = 0; h < 2; h++)
      af[t][h] = *(const bf16x8*)&Qb[(qbase + t * 16 + col) * 64 + quad * 8 + h * 32];
  __syncthreads();
  float linv[4][4];
#pragma unroll
  for (int t = 0; t < 4; t++)
#pragma unroll
    for (int r = 0; r < 4; r++) linv[t][r] = lred[t * 16 + quad * 4 + r];
  const ushort* kp = &Kb[(kbase + w * 16 + col) * 64 + quad * 8];
  bf16x8 nb0 = *(const bf16x8*)kp;
  bf16x8 nb1 = *(const bf16x8*)(kp + 32);
#pragma unroll 1   // rolled: see k_sumexp_l note
  for (int kt = 0; kt < 32; kt++) {
    bf16x8 b0 = nb0, b1 = nb1;
    if (kt < 31) {
      nb0 = *(const bf16x8*)(kp + (size_t)(kt + 1) * 4096);
      nb1 = *(const bf16x8*)(kp + (size_t)(kt + 1) * 4096 + 32);
    }
    float ip = 0.f;
#pragma unroll
    for (int t = 0; t < 4; t++) {
      f32x4 acc = {0.f, 0.f, 0.f, 0.f};
      acc = mfma16(af[t][0], b0, acc);
      acc = mfma16(af[t][1], b1, acc);
#pragma unroll
      for (int r = 0; r < 4; r++) ip += fexp2(acc[r]) * linv[t][r];
    }
    ip += __shfl_xor(ip, 16);   // sum the 4 quad-groups (rows)
    ip += __shfl_xor(ip, 32);
    if (quad == 0)
      IP[((size_t)(b * 64 + qt)) * 4096 + (kh * 32 + kt) * 64 + w * 16 + col] = ip;
  }
}

// Kernel 4a: imp[b][k] = sum_r IP[b*64+r][k] (fixed r order -> deterministic).
__global__ __launch_bounds__(256) void k_impsum(
    const float* __restrict__ IP, float* __restrict__ imp) {
  const int tid = threadIdx.x;
  const int b = blockIdx.y;
  const int col = blockIdx.x * 256 + tid;
  const float* p = IP + (size_t)b * 64 * 4096 + col;
  float s = 0.f;
#pragma unroll 8
  for (int r = 0; r < 64; r++) s += p[(size_t)r * 4096];
  imp[(size_t)b * 4096 + col] = s;
}

// Kernel 4b: exact top-2048 by rank counting (matches lax.top_k ties) and
// rank-indexed gather into compacted Kc/Vc.
__global__ __launch_bounds__(256) void k_mask2c(
    const float* __restrict__ imp, const ushort* __restrict__ Kb,
    const ushort* __restrict__ Vb, ushort* __restrict__ Kc,
    ushort* __restrict__ Vc) {
  __shared__ __align__(16) float imps[4096];
  __shared__ int part[4][64];
  const int tid = threadIdx.x;
  const int b = blockIdx.y;
  const int base = blockIdx.x * 64;
  for (int i = tid; i < 4096; i += 256) imps[i] = imp[(size_t)b * 4096 + i];
  __syncthreads();
  const int cand = tid & 63;
  const int seg = tid >> 6;
  const int k = base + cand;
  const float v = imps[k];
  int cnt = 0;
  const int j0 = seg * 1024;
  for (int j = j0; j < j0 + 1024; j += 4) {
    float4 a = *(const float4*)&imps[j];
    cnt += (a.x > v) ? 1 : ((a.x == v && (j + 0) < k) ? 1 : 0);
    cnt += (a.y > v) ? 1 : ((a.y == v && (j + 1) < k) ? 1 : 0);
    cnt += (a.z > v) ? 1 : ((a.z == v && (j + 2) < k) ? 1 : 0);
    cnt += (a.w > v) ? 1 : ((a.w == v && (j + 3) < k) ? 1 : 0);
  }
  part[seg][cand] = cnt;
  __syncthreads();
  const int c = part[0][cand] + part[1][cand] + part[2][cand] + part[3][cand];
  if (c < 2048) {
    const ushort* ksrc = &Kb[((size_t)b * 4096 + k) * 64 + seg * 16];
    const ushort* vsrc = &Vb[((size_t)b * 4096 + k) * 64 + seg * 16];
    ushort* kdst = &Kc[((size_t)b * 2048 + c) * 64 + seg * 16];
    ushort* vdst = &Vc[((size_t)b * 2048 + c) * 64 + seg * 16];
    *(uint4*)kdst = *(const uint4*)ksrc;
    *(uint4*)(kdst + 8) = *(const uint4*)(ksrc + 8);
    *(uint4*)vdst = *(const uint4*)vsrc;
    *(uint4*)(vdst + 8) = *(const uint4*)(vsrc + 8);
  }
}

// Kernel 5: MFMA attention output + projection over COMPACTED keys (32 tiles).
__global__ __launch_bounds__(256) void k_attn_out(
    const ushort* __restrict__ Qb, const ushort* __restrict__ Kc,
    const ushort* __restrict__ Vc, const float* __restrict__ Lo,
    const float* __restrict__ owp, const float* __restrict__ obp,
    float* __restrict__ out) {
  __shared__ __align__(16) ushort Vt[64][72];   // V transposed: [c][k]
  __shared__ __align__(16) ushort Ps[64][72];   // P (then AO) in A-layout
  __shared__ __align__(16) ushort ows[64][72];  // ow bf16
  __shared__ float dred[4][64];
  __shared__ float lqs[64];
  const int tid = threadIdx.x;
  const int b = blockIdx.x & 7;
  const int qt = blockIdx.x >> 3;
  const int lane = tid & 63;
  const int w = tid >> 6;
  const int col = lane & 15;
  const int quad = lane >> 4;
  const size_t qbase = (size_t)b * 4096 + qt * 64;
  const size_t kbase = (size_t)b * 2048;   // compacted
  bf16x8 af[4][2];
#pragma unroll
  for (int t = 0; t < 4; t++)
#pragma unroll
    for (int h = 0; h < 2; h++)
      af[t][h] = *(const bf16x8*)&Qb[(qbase + t * 16 + col) * 64 + quad * 8 + h * 32];
  for (int i = tid; i < 4096; i += 256) ows[i >> 6][i & 63] = f2bu(owp[i]);
  if (tid < 64) lqs[tid] = Lo[qbase + tid];
  f32x4 pv[4];
  float dpacc[4][4];
#pragma unroll
  for (int t = 0; t < 4; t++) {
    pv[t] = (f32x4){0.f, 0.f, 0.f, 0.f};
#pragma unroll
    for (int r = 0; r < 4; r++) dpacc[t][r] = 0.f;
  }
  const int vrow = tid & 63;   // Vt staging: lane covers one V row,
  const int vch = tid >> 6;    // wave-indexed c-chunk -> conflict-free writes
  const ushort* kp = &Kc[(kbase + w * 16 + col) * 64 + quad * 8];
  bf16x8 nb0 = *(const bf16x8*)kp;
  bf16x8 nb1 = *(const bf16x8*)(kp + 32);
  for (int kt = 0; kt < 32; kt++) {
    __syncthreads();   // prev iteration done reading Vt/Ps
    {
      const ushort* vsrc = &Vc[(kbase + kt * 64 + vrow) * 64 + vch * 16];
      uint4 v0 = *(const uint4*)vsrc;
      uint4 v1 = *(const uint4*)(vsrc + 8);
      ushort tmp[16];
      *(uint4*)&tmp[0] = v0;
      *(uint4*)&tmp[8] = v1;
#pragma unroll
      for (int j = 0; j < 16; j++) Vt[vch * 16 + j][vrow] = tmp[j];
    }
    bf16x8 b0 = nb0, b1 = nb1;
    if (kt < 31) {
      nb0 = *(const bf16x8*)(kp + (size_t)(kt + 1) * 4096);
      nb1 = *(const bf16x8*)(kp + (size_t)(kt + 1) * 4096 + 32);
    }
#pragma unroll
    for (int t = 0; t < 4; t++) {
      f32x4 acc = {0.f, 0.f, 0.f, 0.f};
      acc = mfma16(af[t][0], b0, acc);
      acc = mfma16(af[t][1], b1, acc);
#pragma unroll
      for (int r = 0; r < 4; r++) {
        float p = fexp2(acc[r]);
        dpacc[t][r] += p;
        Ps[t * 16 + quad * 4 + r][w * 16 + col] = f2bu(p);
      }
    }
    __syncthreads();   // Vt + Ps visible
    bf16x8 v0f = *(const bf16x8*)&Vt[w * 16 + col][quad * 8];
    bf16x8 v1f = *(const bf16x8*)&Vt[w * 16 + col][quad * 8 + 32];
#pragma unroll
    for (int t = 0; t < 4; t++) {
      bf16x8 p0 = *(const bf16x8*)&Ps[t * 16 + col][quad * 8];
      bf16x8 p1 = *(const bf16x8*)&Ps[t * 16 + col][quad * 8 + 32];
      pv[t] = mfma16(p0, v0f, pv[t]);
      pv[t] = mfma16(p1, v1f, pv[t]);
    }
  }
  // den: reduce dpacc over the wave's 16 cols, then across waves
#pragma unroll
  for (int t = 0; t < 4; t++)
#pragma unroll
    for (int r = 0; r < 4; r++) {
      float v = dpacc[t][r];
      v += __shfl_xor(v, 1); v += __shfl_xor(v, 2);
      v += __shfl_xor(v, 4); v += __shfl_xor(v, 8);
      if (col == 0) dred[w][t * 16 + quad * 4 + r] = v;
    }
  __syncthreads();
  // normalize pv -> AO (bf16, A-layout in Ps)
#pragma unroll
  for (int t = 0; t < 4; t++)
#pragma unroll
    for (int r = 0; r < 4; r++) {
      int q = t * 16 + quad * 4 + r;
      float den = dred[0][q] + dred[1][q] + dred[2][q] + dred[3][q] + 1e-8f * lqs[q];
      Ps[q][w * 16 + col] = f2bu(pv[t][r] / den);
    }
  __syncthreads();
  // projection: out[q][co] = sum_c AO[q][c]*ow[co][c] + ob[co]
  bf16x8 w0 = *(const bf16x8*)&ows[w * 16 + col][quad * 8];
  bf16x8 w1 = *(const bf16x8*)&ows[w * 16 + col][quad * 8 + 32];
  const float obv = obp[w * 16 + col];
#pragma unroll
  for (int t = 0; t < 4; t++) {
    bf16x8 p0 = *(const bf16x8*)&Ps[t * 16 + col][quad * 8];
    bf16x8 p1 = *(const bf16x8*)&Ps[t * 16 + col][quad * 8 + 32];
    f32x4 oc = {0.f, 0.f, 0.f, 0.f};
    oc = mfma16(p0, w0, oc);
    oc = mfma16(p1, w1, oc);
#pragma unroll
    for (int r = 0; r < 4; r++) {
      int q = t * 16 + quad * 4 + r;
      int co = w * 16 + col;
      out[((size_t)(b * 64 + co)) * 4096 + qt * 64 + q] = oc[r] + obv;
    }
  }
}

extern "C" void kernel_launch(void* const* d_in, const int* in_sizes, int n_in,
                              void* d_out, int out_size, void* d_ws, size_t ws_size,
                              hipStream_t stream) {
  const float* x  = (const float*)d_in[0];
  const float* w1 = (const float*)d_in[1];
  const float* b1 = (const float*)d_in[2];
  const float* w3 = (const float*)d_in[3];
  const float* b3 = (const float*)d_in[4];
  const float* w5 = (const float*)d_in[5];
  const float* b5 = (const float*)d_in[6];
  const float* qw = (const float*)d_in[7];
  const float* qb = (const float*)d_in[8];
  const float* kw = (const float*)d_in[9];
  const float* kb = (const float*)d_in[10];
  const float* vw = (const float*)d_in[11];
  const float* vb = (const float*)d_in[12];
  const float* ow = (const float*)d_in[13];
  const float* ob = (const float*)d_in[14];
  float* out = (float*)d_out;
  float* ws = (float*)d_ws;
  // workspace layout (float units): ~38.5 MB total
  ushort* F    = (ushort*)ws;                 // 6,291,456 us = 3,145,728 f
  ushort* Qb   = (ushort*)(ws + 3145728);     // 1,048,576 f
  ushort* Kb   = (ushort*)(ws + 4194304);     // 1,048,576 f
  ushort* Vb   = (ushort*)(ws + 5242880);     // 1,048,576 f
  float*  Lo   = ws + 6291456;                // 32,768 f
  float*  Linv = ws + 6324224;                // 32,768 f
  float*  Lp   = ws + 6356992;                // 65,536 f
  float*  IP   = ws + 6422528;                // 2,097,152 f
  float*  imp  = ws + 8519680;                // 32,768 f
  ushort* Kc   = (ushort*)(ws + 8552448);     // 524,288 f
  ushort* Vc   = (ushort*)(ws + 9076736);     // 524,288 f
  ushort* Wb   = (ushort*)(ws + 9601024);     // 18,432 f
  float*  w1t  = ws + 9619456;                // 4,096 f

  k_w2b<<<160, 256, 0, stream>>>(qw, kw, vw, w1, Wb, w1t);
  k_conv<<<dim3(64, 8), 256, 0, stream>>>(x, w1t, b1, w3, b3, w5, b5, F);
  k_qkv<<<512, 256, 0, stream>>>(F, Wb, qb, kb, vb, Qb, Kb, Vb);
  k_sumexp_l<<<1024, 256, 0, stream>>>(Qb, Kb, Lp);
  k_lcomb<<<128, 256, 0, stream>>>(Lp, Lo, Linv);
  k_sumexp_ip<<<1024, 256, 0, stream>>>(Qb, Kb, Linv, IP);
  k_impsum<<<dim3(16, 8), 256, 0, stream>>>(IP, imp);
  k_mask2c<<<dim3(64, 8), 256, 0, stream>>>(imp, Kb, Vb, Kc, Vc);
  k_attn_out<<<512, 256, 0, stream>>>(Qb, Kc, Vc, Lo, ow, ob, out);
}

// Round 14
// 304.289 us; speedup vs baseline: 1.2491x; 1.0070x over previous
//
#include <hip/hip_runtime.h>
#include <hip/hip_bf16.h>

typedef unsigned short ushort;
typedef __bf16 bf16x8 __attribute__((ext_vector_type(8)));
typedef float f32x4 __attribute__((ext_vector_type(4)));

__device__ __forceinline__ ushort f2bu(float f) {
  __hip_bfloat16 h = __float2bfloat16(f);
  return *(ushort*)&h;
}
__device__ __forceinline__ float bu2f(ushort u) {
  unsigned int v = ((unsigned int)u) << 16;
  return __uint_as_float(v);
}
__device__ __forceinline__ f32x4 mfma16(bf16x8 a, bf16x8 b, f32x4 c) {
  return __builtin_amdgcn_mfma_f32_16x16x32_bf16(a, b, c, 0, 0, 0);
}
__device__ __forceinline__ float fexp2(float x) { return __builtin_amdgcn_exp2f(x); }

// ---------------------------------------------------------------------------
// Problem constants: B=8, C=64, E=64, H=W=64, N=4096, 3C=192, k_val=2048
// Inputs fp32 / output fp32 (proven round 3). All GEMMs on MFMA.
// Q pre-scaled by 0.125*log2(e): E = 2^score = exp(s/8), single v_exp.
// Round 14: K-split attention output (64-q blocks, 2 K-halves, projection
// commutes with 1/den scaling -> project partial PV, combine kernel divides).
// k_lcomb folded into consumers (Lp read directly). 9 launches.
// ---------------------------------------------------------------------------

// Kernel 1: f_flat[b][n][0:64]=1x1 conv, [64:128]=dw3x3, [128:192]=dw5x5
__global__ __launch_bounds__(256) void k_conv(
    const float* __restrict__ x, const float* __restrict__ w1t, const float* __restrict__ b1,
    const float* __restrict__ w3, const float* __restrict__ b3,
    const float* __restrict__ w5, const float* __restrict__ b5,
    ushort* __restrict__ f) {
  __shared__ ushort Xs[5 * 64 * 74];   // bf16 rows y-2..y+2, data cols 4..67
  const int tid = threadIdx.x;
  const int y = blockIdx.x;
  const int b = blockIdx.y;
  for (int i = tid; i < 320 * 5; i += 256) {
    int r = i / 5, pp = i % 5;
    int col = (pp < 2) ? 2 * pp : 68 + 2 * (pp - 2);
    *(unsigned int*)&Xs[r * 74 + col] = 0u;
  }
#pragma unroll
  for (int k = 0; k < 20; k++) {
    int idx = tid + k * 256;           // 0..5119
    int px4 = idx & 15, ch = (idx >> 4) & 63, yy = idx >> 10;
    int ysrc = y + yy - 2;
    float4 v = make_float4(0.f, 0.f, 0.f, 0.f);
    if (ysrc >= 0 && ysrc < 64)
      v = *(const float4*)&x[(((size_t)(b * 64 + ch) * 64) + ysrc) * 64 + px4 * 4];
    unsigned int lo = (unsigned int)f2bu(v.x) | ((unsigned int)f2bu(v.y) << 16);
    unsigned int hi = (unsigned int)f2bu(v.z) | ((unsigned int)f2bu(v.w) << 16);
    int base = (yy * 64 + ch) * 74 + 4 + px4 * 4;
    *(unsigned int*)&Xs[base] = lo;
    *(unsigned int*)&Xs[base + 2] = hi;
  }
  __syncthreads();
  const int px = tid & 63;
  const int cbu = __builtin_amdgcn_readfirstlane((tid >> 6) * 16);  // wave-uniform
  ushort* fo = f + ((size_t)b * 4096 + y * 64 + px) * 192;
  float a1[16];
#pragma unroll
  for (int j = 0; j < 16; j++) a1[j] = b1[cbu + j];
  for (int ic = 0; ic < 64; ic++) {
    float xv = bu2f(Xs[(2 * 64 + ic) * 74 + 4 + px]);
    const float* wrow = &w1t[ic * 64 + cbu];   // 16 contiguous -> s_load
#pragma unroll
    for (int j = 0; j < 16; j++) a1[j] += wrow[j] * xv;
  }
#pragma unroll
  for (int j = 0; j < 16; j++) fo[cbu + j] = f2bu(a1[j]);
#pragma unroll 4
  for (int j = 0; j < 16; j++) {
    int c = cbu + j;
    float a3 = b3[c], a5 = b5[c];
#pragma unroll
    for (int dy = 0; dy < 5; dy++) {
      const ushort* row = &Xs[(dy * 64 + c) * 74 + 2 + px];
#pragma unroll
      for (int dx = 0; dx < 5; dx++) {
        float v = bu2f(row[dx]);
        a5 += w5[c * 25 + dy * 5 + dx] * v;
        if (dy >= 1 && dy <= 3 && dx >= 1 && dx <= 3)
          a3 += w3[c * 9 + (dy - 1) * 3 + (dx - 1)] * v;
      }
    }
    fo[64 + c] = f2bu(a3);
    fo[128 + c] = f2bu(a5);
  }
}

// Kernel 1b: qw/kw/vw fp32 -> bf16 buffer [3][64][192]; w1 -> w1t (fp32, T).
__global__ __launch_bounds__(256) void k_w2b(
    const float* __restrict__ qw, const float* __restrict__ kw,
    const float* __restrict__ vw, const float* __restrict__ w1,
    ushort* __restrict__ Wb, float* __restrict__ w1t) {
  int i = blockIdx.x * 256 + threadIdx.x;   // 36864 + 4096 total
  if (i < 36864) {
    const float* src = (i < 12288) ? qw : (i < 24576) ? kw : vw;
    int off = (i < 12288) ? i : (i < 24576) ? (i - 12288) : (i - 24576);
    Wb[i] = f2bu(src[off]);
  } else {
    int j = i - 36864;
    if (j < 4096) w1t[(j & 63) * 64 + (j >> 6)] = w1[j];
  }
}

// Kernel 2: Q/K/V = F @ {qw,kw,vw}^T + bias via MFMA. 64 rows/block, 4 waves.
__global__ __launch_bounds__(256) void k_qkv(
    const ushort* __restrict__ F, const ushort* __restrict__ Wb,
    const float* __restrict__ qb, const float* __restrict__ kb,
    const float* __restrict__ vb,
    ushort* __restrict__ Q, ushort* __restrict__ K, ushort* __restrict__ V) {
  __shared__ __align__(16) ushort fs[64][200];   // stride 200: even granule spread
  const int tid = threadIdx.x;
  const int w = tid >> 6;
  const int lane = tid & 63;
  const int col = lane & 15;
  const int quad = lane >> 4;
  const size_t rowbase = (size_t)blockIdx.x * 64;
  for (int i = tid; i < 1536; i += 256) {   // 16B chunks: 64*192*2/16
    int r = i / 24, c8 = i % 24;
    *(uint4*)&fs[r][c8 * 8] = *(const uint4*)&F[rowbase * 192 + (size_t)i * 8];
  }
  __syncthreads();
  bf16x8 af[6];
#pragma unroll
  for (int kk = 0; kk < 6; kk++)
    af[kk] = *(const bf16x8*)&fs[w * 16 + col][kk * 32 + quad * 8];
  ushort* const outp[3] = {Q, K, V};
  const float* const bp[3] = {qb, kb, vb};
#pragma unroll
  for (int sel = 0; sel < 3; sel++) {
    const ushort* wsel = Wb + sel * 12288;
    const float sc = (sel == 0) ? 0.125f * 1.44269504088896f : 1.0f;
#pragma unroll
    for (int ntl = 0; ntl < 4; ntl++) {
      const ushort* brow = wsel + (ntl * 16 + col) * 192 + quad * 8;
      f32x4 acc = {0.f, 0.f, 0.f, 0.f};
#pragma unroll
      for (int kk = 0; kk < 6; kk++) {
        bf16x8 bf = *(const bf16x8*)&brow[kk * 32];
        acc = mfma16(af[kk], bf, acc);
      }
      float bv = bp[sel][ntl * 16 + col];
#pragma unroll
      for (int r = 0; r < 4; r++)
        outp[sel][(rowbase + w * 16 + quad * 4 + r) * 64 + ntl * 16 + col] =
            f2bu((acc[r] + bv) * sc);
    }
  }
}

// Kernel 3a: partial l over one K-half. grid 1024 = 8b x 64qt x 2kh.
__global__ __launch_bounds__(256) void k_sumexp_l(
    const ushort* __restrict__ Qb, const ushort* __restrict__ Kb,
    float* __restrict__ Lp) {
  __shared__ float red[4][64];
  const int tid = threadIdx.x;
  const int b = blockIdx.x & 7;          // XCD swizzle: batch -> XCD
  const int rest = blockIdx.x >> 3;      // 0..127
  const int qt = rest & 63;
  const int kh = rest >> 6;              // K-half
  const int lane = tid & 63;
  const int w = tid >> 6;
  const int col = lane & 15;
  const int quad = lane >> 4;
  const size_t qbase = (size_t)b * 4096 + qt * 64;
  const size_t kbase = (size_t)b * 4096 + kh * 2048;
  bf16x8 af[4][2];
#pragma unroll
  for (int t = 0; t < 4; t++)
#pragma unroll
    for (int h = 0; h < 2; h++)
      af[t][h] = *(const bf16x8*)&Qb[(qbase + t * 16 + col) * 64 + quad * 8 + h * 32];
  const ushort* kp = &Kb[(kbase + w * 16 + col) * 64 + quad * 8];
  float lacc[4][4];
#pragma unroll
  for (int t = 0; t < 4; t++)
#pragma unroll
    for (int r = 0; r < 4; r++) lacc[t][r] = 0.f;
  bf16x8 nb0 = *(const bf16x8*)kp;
  bf16x8 nb1 = *(const bf16x8*)(kp + 32);
#pragma unroll 1   // rolled: full unroll -> 256 VGPR + scratch spill (round 11)
  for (int kt = 0; kt < 32; kt++) {
    bf16x8 b0 = nb0, b1 = nb1;
    if (kt < 31) {
      nb0 = *(const bf16x8*)(kp + (size_t)(kt + 1) * 4096);
      nb1 = *(const bf16x8*)(kp + (size_t)(kt + 1) * 4096 + 32);
    }
#pragma unroll
    for (int t = 0; t < 4; t++) {
      f32x4 acc = {0.f, 0.f, 0.f, 0.f};
      acc = mfma16(af[t][0], b0, acc);
      acc = mfma16(af[t][1], b1, acc);
#pragma unroll
      for (int r = 0; r < 4; r++) lacc[t][r] += fexp2(acc[r]);
    }
  }
#pragma unroll
  for (int t = 0; t < 4; t++)
#pragma unroll
    for (int r = 0; r < 4; r++) {
      float v = lacc[t][r];
      v += __shfl_xor(v, 1); v += __shfl_xor(v, 2);
      v += __shfl_xor(v, 4); v += __shfl_xor(v, 8);
      if (col == 0) red[w][t * 16 + quad * 4 + r] = v;
    }
  __syncthreads();
  if (tid < 64) {
    float l = red[0][tid] + red[1][tid] + red[2][tid] + red[3][tid];
    Lp[((size_t)(b * 64 + qt) * 2 + kh) * 64 + tid] = l;
  }
}

// Kernel 3c: IP sweep over one K-half; Linv computed in-block from Lp.
__global__ __launch_bounds__(256) void k_sumexp_ip(
    const ushort* __restrict__ Qb, const ushort* __restrict__ Kb,
    const float* __restrict__ Lp, float* __restrict__ IP) {
  __shared__ float lred[64];
  const int tid = threadIdx.x;
  const int b = blockIdx.x & 7;
  const int rest = blockIdx.x >> 3;
  const int qt = rest & 63;
  const int kh = rest >> 6;
  const int lane = tid & 63;
  const int w = tid >> 6;
  const int col = lane & 15;
  const int quad = lane >> 4;
  const size_t qbase = (size_t)b * 4096 + qt * 64;
  const size_t kbase = (size_t)b * 4096 + kh * 2048;
  const size_t bqt = (size_t)(b * 64 + qt);
  if (tid < 64)
    lred[tid] = 1.f / (Lp[bqt * 128 + tid] + Lp[bqt * 128 + 64 + tid]);
  bf16x8 af[4][2];
#pragma unroll
  for (int t = 0; t < 4; t++)
#pragma unroll
    for (int h = 0; h < 2; h++)
      af[t][h] = *(const bf16x8*)&Qb[(qbase + t * 16 + col) * 64 + quad * 8 + h * 32];
  __syncthreads();
  float linv[4][4];
#pragma unroll
  for (int t = 0; t < 4; t++)
#pragma unroll
    for (int r = 0; r < 4; r++) linv[t][r] = lred[t * 16 + quad * 4 + r];
  const ushort* kp = &Kb[(kbase + w * 16 + col) * 64 + quad * 8];
  bf16x8 nb0 = *(const bf16x8*)kp;
  bf16x8 nb1 = *(const bf16x8*)(kp + 32);
#pragma unroll 1   // rolled: see k_sumexp_l note
  for (int kt = 0; kt < 32; kt++) {
    bf16x8 b0 = nb0, b1 = nb1;
    if (kt < 31) {
      nb0 = *(const bf16x8*)(kp + (size_t)(kt + 1) * 4096);
      nb1 = *(const bf16x8*)(kp + (size_t)(kt + 1) * 4096 + 32);
    }
    float ip = 0.f;
#pragma unroll
    for (int t = 0; t < 4; t++) {
      f32x4 acc = {0.f, 0.f, 0.f, 0.f};
      acc = mfma16(af[t][0], b0, acc);
      acc = mfma16(af[t][1], b1, acc);
#pragma unroll
      for (int r = 0; r < 4; r++) ip += fexp2(acc[r]) * linv[t][r];
    }
    ip += __shfl_xor(ip, 16);   // sum the 4 quad-groups (rows)
    ip += __shfl_xor(ip, 32);
    if (quad == 0)
      IP[((size_t)(b * 64 + qt)) * 4096 + (kh * 32 + kt) * 64 + w * 16 + col] = ip;
  }
}

// Kernel 4a: imp[b][k] = sum_r IP[b*64+r][k] (fixed r order -> deterministic).
__global__ __launch_bounds__(256) void k_impsum(
    const float* __restrict__ IP, float* __restrict__ imp) {
  const int tid = threadIdx.x;
  const int b = blockIdx.y;
  const int col = blockIdx.x * 256 + tid;
  const float* p = IP + (size_t)b * 64 * 4096 + col;
  float s = 0.f;
#pragma unroll 8
  for (int r = 0; r < 64; r++) s += p[(size_t)r * 4096];
  imp[(size_t)b * 4096 + col] = s;
}

// Kernel 4b: exact top-2048 by rank counting (matches lax.top_k ties) and
// rank-indexed gather into compacted Kc/Vc.
__global__ __launch_bounds__(256) void k_mask2c(
    const float* __restrict__ imp, const ushort* __restrict__ Kb,
    const ushort* __restrict__ Vb, ushort* __restrict__ Kc,
    ushort* __restrict__ Vc) {
  __shared__ __align__(16) float imps[4096];
  __shared__ int part[4][64];
  const int tid = threadIdx.x;
  const int b = blockIdx.y;
  const int base = blockIdx.x * 64;
  for (int i = tid; i < 4096; i += 256) imps[i] = imp[(size_t)b * 4096 + i];
  __syncthreads();
  const int cand = tid & 63;
  const int seg = tid >> 6;
  const int k = base + cand;
  const float v = imps[k];
  int cnt = 0;
  const int j0 = seg * 1024;
  for (int j = j0; j < j0 + 1024; j += 4) {
    float4 a = *(const float4*)&imps[j];
    cnt += (a.x > v) ? 1 : ((a.x == v && (j + 0) < k) ? 1 : 0);
    cnt += (a.y > v) ? 1 : ((a.y == v && (j + 1) < k) ? 1 : 0);
    cnt += (a.z > v) ? 1 : ((a.z == v && (j + 2) < k) ? 1 : 0);
    cnt += (a.w > v) ? 1 : ((a.w == v && (j + 3) < k) ? 1 : 0);
  }
  part[seg][cand] = cnt;
  __syncthreads();
  const int c = part[0][cand] + part[1][cand] + part[2][cand] + part[3][cand];
  if (c < 2048) {
    const ushort* ksrc = &Kb[((size_t)b * 4096 + k) * 64 + seg * 16];
    const ushort* vsrc = &Vb[((size_t)b * 4096 + k) * 64 + seg * 16];
    ushort* kdst = &Kc[((size_t)b * 2048 + c) * 64 + seg * 16];
    ushort* vdst = &Vc[((size_t)b * 2048 + c) * 64 + seg * 16];
    *(uint4*)kdst = *(const uint4*)ksrc;
    *(uint4*)(kdst + 8) = *(const uint4*)(ksrc + 8);
    *(uint4*)vdst = *(const uint4*)vsrc;
    *(uint4*)(vdst + 8) = *(const uint4*)(vsrc + 8);
  }
}

// Kernel 5a: partial attention output over one compacted-K half (16 tiles).
// Projection commutes with 1/den: OPp = ow @ PV_half (unnormalized),
// Dp = partial den. grid 1024 = 8b x 64qt x 2kh.
__global__ __launch_bounds__(256) void k_attn_po(
    const ushort* __restrict__ Qb, const ushort* __restrict__ Kc,
    const ushort* __restrict__ Vc, const float* __restrict__ owp,
    float* __restrict__ OPp, float* __restrict__ Dp) {
  __shared__ __align__(16) ushort Vt[64][72];   // V transposed: [c][k]
  __shared__ __align__(16) ushort Ps[64][72];   // P (then PV) in A-layout
  __shared__ __align__(16) ushort ows[64][72];  // ow bf16
  __shared__ float dred[4][64];
  const int tid = threadIdx.x;
  const int b = blockIdx.x & 7;
  const int rest = blockIdx.x >> 3;
  const int qt = rest & 63;
  const int kh = rest >> 6;
  const int lane = tid & 63;
  const int w = tid >> 6;
  const int col = lane & 15;
  const int quad = lane >> 4;
  const size_t qbase = (size_t)b * 4096 + qt * 64;
  const size_t kbase = (size_t)b * 2048 + kh * 1024;   // compacted half
  const size_t bidx = (size_t)(b * 64 + qt) * 2 + kh;
  bf16x8 af[4][2];
#pragma unroll
  for (int t = 0; t < 4; t++)
#pragma unroll
    for (int h = 0; h < 2; h++)
      af[t][h] = *(const bf16x8*)&Qb[(qbase + t * 16 + col) * 64 + quad * 8 + h * 32];
  for (int i = tid; i < 4096; i += 256) ows[i >> 6][i & 63] = f2bu(owp[i]);
  f32x4 pv[4];
  float dpacc[4][4];
#pragma unroll
  for (int t = 0; t < 4; t++) {
    pv[t] = (f32x4){0.f, 0.f, 0.f, 0.f};
#pragma unroll
    for (int r = 0; r < 4; r++) dpacc[t][r] = 0.f;
  }
  const int vrow = tid & 63;   // Vt staging: lane covers one V row,
  const int vch = tid >> 6;    // wave-indexed c-chunk -> conflict-free writes
  const ushort* kp = &Kc[(kbase + w * 16 + col) * 64 + quad * 8];
  bf16x8 nb0 = *(const bf16x8*)kp;
  bf16x8 nb1 = *(const bf16x8*)(kp + 32);
#pragma unroll 1
  for (int kt = 0; kt < 16; kt++) {
    __syncthreads();   // prev iteration done reading Vt/Ps
    {
      const ushort* vsrc = &Vc[(kbase + kt * 64 + vrow) * 64 + vch * 16];
      uint4 v0 = *(const uint4*)vsrc;
      uint4 v1 = *(const uint4*)(vsrc + 8);
      ushort tmp[16];
      *(uint4*)&tmp[0] = v0;
      *(uint4*)&tmp[8] = v1;
#pragma unroll
      for (int j = 0; j < 16; j++) Vt[vch * 16 + j][vrow] = tmp[j];
    }
    bf16x8 b0 = nb0, b1 = nb1;
    if (kt < 15) {
      nb0 = *(const bf16x8*)(kp + (size_t)(kt + 1) * 4096);
      nb1 = *(const bf16x8*)(kp + (size_t)(kt + 1) * 4096 + 32);
    }
#pragma unroll
    for (int t = 0; t < 4; t++) {
      f32x4 acc = {0.f, 0.f, 0.f, 0.f};
      acc = mfma16(af[t][0], b0, acc);
      acc = mfma16(af[t][1], b1, acc);
#pragma unroll
      for (int r = 0; r < 4; r++) {
        float p = fexp2(acc[r]);
        dpacc[t][r] += p;
        Ps[t * 16 + quad * 4 + r][w * 16 + col] = f2bu(p);
      }
    }
    __syncthreads();   // Vt + Ps visible
    bf16x8 v0f = *(const bf16x8*)&Vt[w * 16 + col][quad * 8];
    bf16x8 v1f = *(const bf16x8*)&Vt[w * 16 + col][quad * 8 + 32];
#pragma unroll
    for (int t = 0; t < 4; t++) {
      bf16x8 p0 = *(const bf16x8*)&Ps[t * 16 + col][quad * 8];
      bf16x8 p1 = *(const bf16x8*)&Ps[t * 16 + col][quad * 8 + 32];
      pv[t] = mfma16(p0, v0f, pv[t]);
      pv[t] = mfma16(p1, v1f, pv[t]);
    }
  }
  // partial den: reduce over wave's 16 cols, then across waves
#pragma unroll
  for (int t = 0; t < 4; t++)
#pragma unroll
    for (int r = 0; r < 4; r++) {
      float v = dpacc[t][r];
      v += __shfl_xor(v, 1); v += __shfl_xor(v, 2);
      v += __shfl_xor(v, 4); v += __shfl_xor(v, 8);
      if (col == 0) dred[w][t * 16 + quad * 4 + r] = v;
    }
  __syncthreads();
  if (tid < 64)
    Dp[bidx * 64 + tid] = dred[0][tid] + dred[1][tid] + dred[2][tid] + dred[3][tid];
  // partial PV (unnormalized) -> bf16 A-layout in Ps
#pragma unroll
  for (int t = 0; t < 4; t++)
#pragma unroll
    for (int r = 0; r < 4; r++)
      Ps[t * 16 + quad * 4 + r][w * 16 + col] = f2bu(pv[t][r]);
  __syncthreads();
  // projection of partial PV: OPp[bidx][q][co]
  bf16x8 w0 = *(const bf16x8*)&ows[w * 16 + col][quad * 8];
  bf16x8 w1 = *(const bf16x8*)&ows[w * 16 + col][quad * 8 + 32];
#pragma unroll
  for (int t = 0; t < 4; t++) {
    bf16x8 p0 = *(const bf16x8*)&Ps[t * 16 + col][quad * 8];
    bf16x8 p1 = *(const bf16x8*)&Ps[t * 16 + col][quad * 8 + 32];
    f32x4 oc = {0.f, 0.f, 0.f, 0.f};
    oc = mfma16(p0, w0, oc);
    oc = mfma16(p1, w1, oc);
#pragma unroll
    for (int r = 0; r < 4; r++) {
      int q = t * 16 + quad * 4 + r;
      int co = w * 16 + col;
      OPp[bidx * 4096 + q * 64 + co] = oc[r];
    }
  }
}

// Kernel 5b: combine halves: out = (OPa+OPb)/(Da+Db+1e-8*(La+Lb)) + ob.
// LDS transpose so final stores are 64-float contiguous per co.
__global__ __launch_bounds__(256) void k_attn_comb(
    const float* __restrict__ OPp, const float* __restrict__ Dp,
    const float* __restrict__ Lp, const float* __restrict__ obp,
    float* __restrict__ out) {
  __shared__ float T[64 * 65];
  __shared__ float rden[64];
  __shared__ float obs[64];
  const int tid = threadIdx.x;
  const int b = blockIdx.x & 7;
  const int qt = blockIdx.x >> 3;
  const size_t bqt = (size_t)(b * 64 + qt);
  if (tid < 64) {
    float d = Dp[bqt * 128 + tid] + Dp[bqt * 128 + 64 + tid];
    float l = Lp[bqt * 128 + tid] + Lp[bqt * 128 + 64 + tid];
    rden[tid] = 1.f / (d + 1e-8f * l);
    obs[tid] = obp[tid];
  }
  __syncthreads();
  const float* A = OPp + bqt * 2 * 4096;
  const float* Bh = A + 4096;
  for (int i = tid; i < 4096; i += 256) {
    int q = i >> 6, co = i & 63;
    T[co * 65 + q] = (A[i] + Bh[i]) * rden[q];
  }
  __syncthreads();
  for (int i = tid; i < 4096; i += 256) {
    int co = i >> 6, q = i & 63;
    out[((size_t)(b * 64 + co)) * 4096 + qt * 64 + q] = T[co * 65 + q] + obs[co];
  }
}

extern "C" void kernel_launch(void* const* d_in, const int* in_sizes, int n_in,
                              void* d_out, int out_size, void* d_ws, size_t ws_size,
                              hipStream_t stream) {
  const float* x  = (const float*)d_in[0];
  const float* w1 = (const float*)d_in[1];
  const float* b1 = (const float*)d_in[2];
  const float* w3 = (const float*)d_in[3];
  const float* b3 = (const float*)d_in[4];
  const float* w5 = (const float*)d_in[5];
  const float* b5 = (const float*)d_in[6];
  const float* qw = (const float*)d_in[7];
  const float* qb = (const float*)d_in[8];
  const float* kw = (const float*)d_in[9];
  const float* kb = (const float*)d_in[10];
  const float* vw = (const float*)d_in[11];
  const float* vb = (const float*)d_in[12];
  const float* ow = (const float*)d_in[13];
  const float* ob = (const float*)d_in[14];
  float* out = (float*)d_out;
  float* ws = (float*)d_ws;
  // workspace layout (float units): ~55.3 MB total
  ushort* F    = (ushort*)ws;                 // 3,145,728 f
  ushort* Qb   = (ushort*)(ws + 3145728);     // 1,048,576 f
  ushort* Kb   = (ushort*)(ws + 4194304);     // 1,048,576 f
  ushort* Vb   = (ushort*)(ws + 5242880);     // 1,048,576 f
  float*  Lp   = ws + 6291456;                // 65,536 f
  float*  IP   = ws + 6356992;                // 2,097,152 f
  float*  imp  = ws + 8454144;                // 32,768 f
  ushort* Kc   = (ushort*)(ws + 8486912);     // 524,288 f
  ushort* Vc   = (ushort*)(ws + 9011200);     // 524,288 f
  ushort* Wb   = (ushort*)(ws + 9535488);     // 18,432 f
  float*  w1t  = ws + 9553920;                // 4,096 f
  float*  OPp  = ws + 9558016;                // 4,194,304 f
  float*  Dp   = ws + 13752320;               // 65,536 f

  k_w2b<<<160, 256, 0, stream>>>(qw, kw, vw, w1, Wb, w1t);
  k_conv<<<dim3(64, 8), 256, 0, stream>>>(x, w1t, b1, w3, b3, w5, b5, F);
  k_qkv<<<512, 256, 0, stream>>>(F, Wb, qb, kb, vb, Qb, Kb, Vb);
  k_sumexp_l<<<1024, 256, 0, stream>>>(Qb, Kb, Lp);
  k_sumexp_ip<<<1024, 256, 0, stream>>>(Qb, Kb, Lp, IP);
  k_impsum<<<dim3(16, 8), 256, 0, stream>>>(IP, imp);
  k_mask2c<<<dim3(64, 8), 256, 0, stream>>>(imp, Kb, Vb, Kc, Vc);
  k_attn_po<<<1024, 256, 0, stream>>>(Qb, Kc, Vc, ow, OPp, Dp);
  k_attn_comb<<<512, 256, 0, stream>>>(OPp, Dp, Lp, ob, out);
}